// Round 2
// baseline (2107.902 us; speedup 1.0000x reference)
//
#include <hip/hip_runtime.h>
#include <math.h>

__device__ __forceinline__ float wred_sum(float v){
  #pragma unroll
  for (int o = 32; o > 0; o >>= 1) v += __shfl_xor(v, o);
  return v;
}
__device__ __forceinline__ float wred_max(float v){
  #pragma unroll
  for (int o = 32; o > 0; o >>= 1) v = fmaxf(v, __shfl_xor(v, o));
  return v;
}
__device__ __forceinline__ float lrelu(float v){ return v > 0.f ? v : 0.2f * v; }

// ---------------- CSR build (dst-sorted) ----------------
__global__ void k_hist(const int* __restrict__ dst, int* __restrict__ deg, int E){
  int t = blockIdx.x * blockDim.x + threadIdx.x;
  if (t < E) atomicAdd(&deg[dst[t]], 1);
}

__global__ void k_scan_rowptr(const int* __restrict__ deg, int* __restrict__ rowptr, int n){
  __shared__ int ssum[256];
  int t = threadIdx.x;
  int seg = (n + 255) / 256;
  int lo = t * seg; if (lo > n) lo = n;
  int hi = lo + seg; if (hi > n) hi = n;
  int s = 0;
  for (int i = lo; i < hi; i++) s += deg[i];
  ssum[t] = s;
  __syncthreads();
  for (int o = 1; o < 256; o <<= 1){
    int v = 0;
    if (t >= o) v = ssum[t - o];
    __syncthreads();
    ssum[t] += v;
    __syncthreads();
  }
  int run = (t > 0) ? ssum[t - 1] : 0;
  for (int i = lo; i < hi; i++){ rowptr[i] = run; run += deg[i]; }
  if (t == 255) rowptr[n] = ssum[255];
}

__global__ void k_scatter(const int* __restrict__ src, const int* __restrict__ dst,
                          int* __restrict__ cursor, int* __restrict__ esrc, int E){
  int t = blockIdx.x * blockDim.x + threadIdx.x;
  if (t < E){
    int d = dst[t];
    int p = atomicAdd(&cursor[d], 1);
    esrc[p] = src[t];
  }
}

// ---------------- GEMM z = x @ W^T (+ el/er attention logits) ----------------
// wave per row; lane holds cols {j*64+lane}. H=0: no el/er. H==1: single head over
// all C cols. H>1: requires H == C/64 (head j == reg j).
template<int K, int C, int H>
__global__ void k_gemm(const float* __restrict__ x, const float* __restrict__ W,
                       const float* __restrict__ al, const float* __restrict__ ar,
                       float* __restrict__ z, float* __restrict__ el, float* __restrict__ er,
                       int n){
  constexpr int KR = K / 64, CR = C / 64;
  int lane = threadIdx.x & 63;
  int i = blockIdx.x * (blockDim.x >> 6) + (threadIdx.x >> 6);
  if (i >= n) return;
  const float* xr = x + (size_t)i * K;
  float xv[KR];
  #pragma unroll
  for (int j = 0; j < KR; j++) xv[j] = xr[j * 64 + lane];
  float acc[CR];
  #pragma unroll
  for (int j = 0; j < CR; j++) acc[j] = 0.f;
  #pragma unroll
  for (int k = 0; k < K; k++){
    float xk = __shfl(xv[k >> 6], k & 63);
    #pragma unroll
    for (int j = 0; j < CR; j++) acc[j] += xk * W[(size_t)(j * 64 + lane) * K + k];
  }
  float* zr = z + (size_t)i * C;
  #pragma unroll
  for (int j = 0; j < CR; j++) zr[j * 64 + lane] = acc[j];
  if constexpr (H == 1){
    float pl = 0.f, pr = 0.f;
    #pragma unroll
    for (int j = 0; j < CR; j++){
      int c = j * 64 + lane;
      pl += acc[j] * al[c];
      pr += acc[j] * ar[c];
    }
    pl = wred_sum(pl); pr = wred_sum(pr);
    if (lane == 0){ el[i] = pl; er[i] = pr; }
  } else if constexpr (H > 1){
    #pragma unroll
    for (int j = 0; j < CR; j++){
      int c = j * 64 + lane;
      float pl = wred_sum(acc[j] * al[c]);
      float pr = wred_sum(acc[j] * ar[c]);
      if (lane == 0){ el[(size_t)i * H + j] = pl; er[(size_t)i * H + j] = pr; }
    }
  }
}

// ---------------- GAT aggregation, 1 head, fused with chain-shift + mean ----------------
// out[i] = 0.5*( (deg?  (Σ w z[s])/Σw : 0) + b  +  (i>0? zb[i-1]:0) + bb )
template<int D>
__global__ void k_gat_h1(const int* __restrict__ rowptr, const int* __restrict__ esrc,
                         const float* __restrict__ z, const float* __restrict__ el,
                         const float* __restrict__ er, const float* __restrict__ b,
                         const float* __restrict__ zb, const float* __restrict__ bb,
                         float* __restrict__ out, int n){
  constexpr int DR = D / 64;
  int lane = threadIdx.x & 63;
  int i = blockIdx.x * (blockDim.x >> 6) + (threadIdx.x >> 6);
  if (i >= n) return;
  int s0 = rowptr[i], s1 = rowptr[i + 1];
  float eri = er[i];
  float m = -INFINITY;
  for (int e = s0 + lane; e < s1; e += 64)
    m = fmaxf(m, lrelu(el[esrc[e]] + eri));
  m = wred_max(m);
  float den = 0.f;
  float acc[DR];
  #pragma unroll
  for (int j = 0; j < DR; j++) acc[j] = 0.f;
  for (int e = s0; e < s1; ++e){
    int s = esrc[e];
    float w = __expf(lrelu(el[s] + eri) - m);
    den += w;
    const float* zs = z + (size_t)s * D;
    #pragma unroll
    for (int j = 0; j < DR; j++) acc[j] += w * zs[j * 64 + lane];
  }
  float inv = (s1 > s0) ? 1.f / den : 0.f;
  float* op = out + (size_t)i * D;
  #pragma unroll
  for (int j = 0; j < DR; j++){
    int c = j * 64 + lane;
    float chain = bb[c];
    if (i > 0) chain += zb[(size_t)(i - 1) * D + c];
    op[c] = 0.5f * ((acc[j] * inv + b[c]) + chain);
  }
}

// ---------------- GAT aggregation, 4 heads x 64 dims ----------------
__global__ void k_gat_mh(const int* __restrict__ rowptr, const int* __restrict__ esrc,
                         const float* __restrict__ z, const float* __restrict__ el,
                         const float* __restrict__ er, const float* __restrict__ b,
                         const float* __restrict__ zb, const float* __restrict__ bb,
                         float* __restrict__ out, int n){
  int lane = threadIdx.x & 63;
  int i = blockIdx.x * (blockDim.x >> 6) + (threadIdx.x >> 6);
  if (i >= n) return;
  int s0 = rowptr[i], s1 = rowptr[i + 1];
  const float4 eri = *(const float4*)(er + (size_t)i * 4);
  float m0 = -INFINITY, m1 = -INFINITY, m2 = -INFINITY, m3 = -INFINITY;
  for (int e = s0 + lane; e < s1; e += 64){
    float4 e4 = *(const float4*)(el + (size_t)esrc[e] * 4);
    m0 = fmaxf(m0, lrelu(e4.x + eri.x));
    m1 = fmaxf(m1, lrelu(e4.y + eri.y));
    m2 = fmaxf(m2, lrelu(e4.z + eri.z));
    m3 = fmaxf(m3, lrelu(e4.w + eri.w));
  }
  m0 = wred_max(m0); m1 = wred_max(m1); m2 = wred_max(m2); m3 = wred_max(m3);
  float d0 = 0.f, d1 = 0.f, d2 = 0.f, d3 = 0.f;
  float a0 = 0.f, a1 = 0.f, a2 = 0.f, a3 = 0.f;
  for (int e = s0; e < s1; ++e){
    int s = esrc[e];
    float4 e4 = *(const float4*)(el + (size_t)s * 4);
    float w0 = __expf(lrelu(e4.x + eri.x) - m0);
    float w1 = __expf(lrelu(e4.y + eri.y) - m1);
    float w2 = __expf(lrelu(e4.z + eri.z) - m2);
    float w3 = __expf(lrelu(e4.w + eri.w) - m3);
    d0 += w0; d1 += w1; d2 += w2; d3 += w3;
    const float* zs = z + (size_t)s * 256;
    a0 += w0 * zs[lane];
    a1 += w1 * zs[64 + lane];
    a2 += w2 * zs[128 + lane];
    a3 += w3 * zs[192 + lane];
  }
  float has = (s1 > s0) ? 1.f : 0.f;
  a0 = (has != 0.f) ? a0 / d0 : 0.f;
  a1 = (has != 0.f) ? a1 / d1 : 0.f;
  a2 = (has != 0.f) ? a2 / d2 : 0.f;
  a3 = (has != 0.f) ? a3 / d3 : 0.f;
  float* op = out + (size_t)i * 256;
  float av[4] = {a0, a1, a2, a3};
  #pragma unroll
  for (int h = 0; h < 4; h++){
    int c = h * 64 + lane;
    float chain = bb[c];
    if (i > 0) chain += zb[(size_t)(i - 1) * 256 + c];
    op[c] = 0.5f * ((av[h] + b[c]) + chain);
  }
}

// ---------------- chain_pass: m_i = h[i-1]-h[i], L2-normalize last dim ----------------
__global__ void k_chainpass64(const float* __restrict__ h, float* __restrict__ dh, int n){
  int lane = threadIdx.x & 63;
  int i = blockIdx.x * (blockDim.x >> 6) + (threadIdx.x >> 6);
  if (i >= n) return;
  float d = 0.f;
  if (i > 0) d = h[(size_t)(i - 1) * 64 + lane] - h[(size_t)i * 64 + lane];
  float ss = wred_sum(d * d);
  dh[(size_t)i * 64 + lane] = d / (sqrtf(ss) + 1e-7f);
}

__global__ void k_chainpass_mh(const float* __restrict__ hm, float* __restrict__ ds, int n){
  int lane = threadIdx.x & 63;
  int i = blockIdx.x * (blockDim.x >> 6) + (threadIdx.x >> 6);
  if (i >= n) return;
  const float* cur = hm + (size_t)i * 256;
  const float* prv = hm + (size_t)(i - 1) * 256;
  #pragma unroll
  for (int h = 0; h < 4; h++){
    int c = h * 64 + lane;
    float d = (i > 0) ? (prv[c] - cur[c]) : 0.f;
    float ss = wred_sum(d * d);
    ds[(size_t)i * 256 + c] = d / (sqrtf(ss) + 1e-7f);
  }
}

// ---------------- column-wise prefix sum over nodes (256 cols) ----------------
__global__ void k_chunk_sum(const float* __restrict__ ds, float* __restrict__ csum, int n, int ch){
  int b = blockIdx.x, t = threadIdx.x;
  int r0 = b * ch, r1 = r0 + ch; if (r1 > n) r1 = n;
  float s = 0.f;
  for (int r = r0; r < r1; r++) s += ds[(size_t)r * 256 + t];
  csum[(size_t)b * 256 + t] = s;
}
__global__ void k_scan_chunks(float* __restrict__ csum, int nb){
  int t = threadIdx.x;
  float run = 0.f;
  for (int b = 0; b < nb; b++){
    float v = csum[(size_t)b * 256 + t];
    csum[(size_t)b * 256 + t] = run;
    run += v;
  }
}
__global__ void k_apply_scan(float* __restrict__ ds, const float* __restrict__ csum, int n, int ch){
  int b = blockIdx.x, t = threadIdx.x;
  int r0 = b * ch, r1 = r0 + ch; if (r1 > n) r1 = n;
  float run = csum[(size_t)b * 256 + t];
  for (int r = r0; r < r1; r++){
    run += ds[(size_t)r * 256 + t];
    ds[(size_t)r * 256 + t] = run;
  }
}

extern "C" void kernel_launch(void* const* d_in, const int* in_sizes, int n_in,
                              void* d_out, int out_size, void* d_ws, size_t ws_size,
                              hipStream_t stream){
  const float* x    = (const float*)d_in[0];
  const int*   src0 = (const int*)d_in[1];
  const int*   dst0 = (const int*)d_in[2];
  // d_in[3]=src1, d_in[4]=dst1: chain graph is arange -> handled analytically.
  const float* W1a  = (const float*)d_in[5];
  const float* al1a = (const float*)d_in[6];
  const float* ar1a = (const float*)d_in[7];
  const float* b1a  = (const float*)d_in[8];
  const float* W1b  = (const float*)d_in[9];
  const float* b1b  = (const float*)d_in[12];
  const float* W2a  = (const float*)d_in[13];
  const float* al2a = (const float*)d_in[14];
  const float* ar2a = (const float*)d_in[15];
  const float* b2a  = (const float*)d_in[16];
  const float* W2b  = (const float*)d_in[17];
  const float* b2b  = (const float*)d_in[20];
  const float* Wma  = (const float*)d_in[21];
  const float* alma = (const float*)d_in[22];
  const float* arma = (const float*)d_in[23];
  const float* bma  = (const float*)d_in[24];
  const float* Wmb  = (const float*)d_in[25];
  const float* bmb  = (const float*)d_in[28];

  const int n = in_sizes[0] / 64;
  const int E = in_sizes[1];
  const size_t nf = (size_t)n;

  // workspace layout (fp32): A,B,C are n*256; D2,E2 are n*64; attention logits; scan; CSR
  float* ws  = (float*)d_ws;
  float* A   = ws;
  float* B   = A + nf * 256;
  float* C   = B + nf * 256;
  float* D2  = C + nf * 256;   // h2 [n,64]
  float* E2  = D2 + nf * 64;   // dh [n,64]
  float* ela = E2 + nf * 64;   // [n,4] (only [n] used for 1-head layers)
  float* era = ela + nf * 4;
  const int ch = 100;
  const int nb = (n + ch - 1) / ch;
  float* csum = era + nf * 4;  // [nb,256]
  int* deg    = (int*)(csum + (size_t)nb * 256);
  int* rowptr = deg + n;
  int* cursor = rowptr + (n + 1);
  int* esrc   = cursor + n;

  float* dsout = (float*)d_out;   // ds staged in d_out, scanned in-place

  const int nwb = (n + 3) / 4;      // 4 waves (nodes) per 256-thread block
  const int eb  = (E + 255) / 256;

  // CSR of interacts graph by dst (shared by all three GAT layers)
  hipMemsetAsync(deg, 0, (size_t)n * sizeof(int), stream);
  k_hist<<<eb, 256, 0, stream>>>(dst0, deg, E);
  k_scan_rowptr<<<1, 256, 0, stream>>>(deg, rowptr, n);
  hipMemcpyAsync(cursor, rowptr, (size_t)n * sizeof(int), hipMemcpyDeviceToDevice, stream);
  k_scatter<<<eb, 256, 0, stream>>>(src0, dst0, cursor, esrc, E);

  // layer 1: in=64 -> hid=128
  k_gemm<64, 128, 1><<<nwb, 256, 0, stream>>>(x, W1a, al1a, ar1a, A, ela, era, n);
  k_gemm<64, 128, 0><<<nwb, 256, 0, stream>>>(x, W1b, nullptr, nullptr, B, nullptr, nullptr, n);
  k_gat_h1<128><<<nwb, 256, 0, stream>>>(rowptr, esrc, A, ela, era, b1a, B, b1b, C, n);

  // layer 2: hid=128 -> out=64
  k_gemm<128, 64, 1><<<nwb, 256, 0, stream>>>(C, W2a, al2a, ar2a, A, ela, era, n);
  k_gemm<128, 64, 0><<<nwb, 256, 0, stream>>>(C, W2b, nullptr, nullptr, B, nullptr, nullptr, n);
  k_gat_h1<64><<<nwb, 256, 0, stream>>>(rowptr, esrc, A, ela, era, b2a, B, b2b, D2, n);

  // dh = chain_pass(h2); conh = cumsum over singleton axis = dh
  k_chainpass64<<<nwb, 256, 0, stream>>>(D2, E2, n);

  // MH layer: out=64 -> 4 heads x 64
  k_gemm<64, 256, 4><<<nwb, 256, 0, stream>>>(E2, Wma, alma, arma, A, ela, era, n);
  k_gemm<64, 256, 0><<<nwb, 256, 0, stream>>>(E2, Wmb, nullptr, nullptr, B, nullptr, nullptr, n);
  k_gat_mh<<<nwb, 256, 0, stream>>>(rowptr, esrc, A, ela, era, bma, B, bmb, C, n);

  // ds = chain_pass(hm) -> staged directly in d_out
  k_chainpass_mh<<<nwb, 256, 0, stream>>>(C, dsout, n);

  // res = cumsum(ds, axis=0), in-place in d_out
  k_chunk_sum<<<nb, 256, 0, stream>>>(dsout, csum, n, ch);
  k_scan_chunks<<<1, 256, 0, stream>>>(csum, nb);
  k_apply_scan<<<nb, 256, 0, stream>>>(dsout, csum, n, ch);
}

// Round 3
// 972.687 us; speedup vs baseline: 2.1671x; 2.1671x over previous
//
#include <hip/hip_runtime.h>
#include <math.h>

__device__ __forceinline__ float wred_sum(float v){
  #pragma unroll
  for (int o = 32; o > 0; o >>= 1) v += __shfl_xor(v, o);
  return v;
}
__device__ __forceinline__ float wred_max(float v){
  #pragma unroll
  for (int o = 32; o > 0; o >>= 1) v = fmaxf(v, __shfl_xor(v, o));
  return v;
}
__device__ __forceinline__ float lrelu(float v){ return v > 0.f ? v : 0.2f * v; }

// ---------------- CSR build (dst-sorted) ----------------
__global__ void k_hist(const int* __restrict__ dst, int* __restrict__ deg, int E){
  int t = blockIdx.x * blockDim.x + threadIdx.x;
  if (t < E) atomicAdd(&deg[dst[t]], 1);
}

__global__ void k_scan_rowptr(const int* __restrict__ deg, int* __restrict__ rowptr, int n){
  __shared__ int ssum[256];
  int t = threadIdx.x;
  int seg = (n + 255) / 256;
  int lo = t * seg; if (lo > n) lo = n;
  int hi = lo + seg; if (hi > n) hi = n;
  int s = 0;
  for (int i = lo; i < hi; i++) s += deg[i];
  ssum[t] = s;
  __syncthreads();
  for (int o = 1; o < 256; o <<= 1){
    int v = 0;
    if (t >= o) v = ssum[t - o];
    __syncthreads();
    ssum[t] += v;
    __syncthreads();
  }
  int run = (t > 0) ? ssum[t - 1] : 0;
  for (int i = lo; i < hi; i++){ rowptr[i] = run; run += deg[i]; }
  if (t == 255) rowptr[n] = ssum[255];
}

__global__ void k_scatter(const int* __restrict__ src, const int* __restrict__ dst,
                          int* __restrict__ cursor, int* __restrict__ esrc, int E){
  int t = blockIdx.x * blockDim.x + threadIdx.x;
  if (t < E){
    int d = dst[t];
    int p = atomicAdd(&cursor[d], 1);
    esrc[p] = src[t];
  }
}

// ---------------- GEMM z = x @ W^T (+ el/er attention logits) ----------------
// Block = 256 threads = 4 waves; each wave computes R=8 rows; block = 32 rows.
// W staged transposed in LDS as float4-over-k: WQ[k4][c] (row padded +1 float4),
// so inner-loop W reads are conflict-free ds_read_b128 (consecutive lanes ->
// consecutive banks). x rows staged in LDS, read at wave-uniform addresses
// (broadcast). No shfl in the hot loop.
template<int K, int C, int H>
__global__ void k_gemm(const float* __restrict__ x, const float* __restrict__ W,
                       const float* __restrict__ al, const float* __restrict__ ar,
                       float* __restrict__ z, float* __restrict__ el, float* __restrict__ er,
                       int n){
  constexpr int K4 = K / 4;
  constexpr int CR = C / 64;
  constexpr int CP = C + 1;      // padded W row length in float4 units
  constexpr int R = 8;           // rows per wave
  constexpr int ROWS = 4 * R;    // rows per block
  __shared__ float4 WQ[K4 * CP];
  __shared__ float  XS[ROWS][K];

  int t = threadIdx.x;
  int lane = t & 63, wv = t >> 6;
  int rowbase = blockIdx.x * ROWS;

  // stage W: global float4 reads coalesced; LDS writes ~2-way conflict (one-time)
  const float4* W4 = (const float4*)W;
  for (int idx = t; idx < C * K4; idx += 256){
    int c = idx / K4, k4 = idx - c * K4;
    WQ[k4 * CP + c] = W4[idx];
  }
  // stage x rows (coalesced)
  for (int idx = t; idx < ROWS * K; idx += 256){
    int r = idx / K, k = idx - r * K;
    int row = rowbase + r;
    XS[r][k] = (row < n) ? x[(size_t)row * K + k] : 0.f;
  }
  __syncthreads();

  float acc[R][CR];
  #pragma unroll
  for (int r = 0; r < R; r++)
    #pragma unroll
    for (int j = 0; j < CR; j++) acc[r][j] = 0.f;

  const int r0 = wv * R;
  #pragma unroll 4
  for (int k4 = 0; k4 < K4; k4++){
    float4 wq[CR];
    #pragma unroll
    for (int j = 0; j < CR; j++) wq[j] = WQ[k4 * CP + j * 64 + lane];
    #pragma unroll
    for (int r = 0; r < R; r++){
      float4 xk = *(const float4*)&XS[r0 + r][k4 * 4];
      #pragma unroll
      for (int j = 0; j < CR; j++){
        acc[r][j] += xk.x * wq[j].x;
        acc[r][j] += xk.y * wq[j].y;
        acc[r][j] += xk.z * wq[j].z;
        acc[r][j] += xk.w * wq[j].w;
      }
    }
  }

  float alv[CR], arv[CR];
  if constexpr (H > 0){
    #pragma unroll
    for (int j = 0; j < CR; j++){ alv[j] = al[j * 64 + lane]; arv[j] = ar[j * 64 + lane]; }
  }

  #pragma unroll
  for (int r = 0; r < R; r++){
    int row = rowbase + r0 + r;
    if (row >= n) continue;
    float* zr = z + (size_t)row * C;
    #pragma unroll
    for (int j = 0; j < CR; j++) zr[j * 64 + lane] = acc[r][j];
    if constexpr (H == 1){
      float pl = 0.f, pr = 0.f;
      #pragma unroll
      for (int j = 0; j < CR; j++){ pl += acc[r][j] * alv[j]; pr += acc[r][j] * arv[j]; }
      pl = wred_sum(pl); pr = wred_sum(pr);
      if (lane == 0){ el[row] = pl; er[row] = pr; }
    } else if constexpr (H > 1){
      #pragma unroll
      for (int j = 0; j < CR; j++){
        float pl = wred_sum(acc[r][j] * alv[j]);
        float pr = wred_sum(acc[r][j] * arv[j]);
        if (lane == 0){ el[(size_t)row * H + j] = pl; er[(size_t)row * H + j] = pr; }
      }
    }
  }
}

// ---------------- GAT aggregation, 1 head, fused with chain-shift + mean ----------------
// out[i] = 0.5*( (deg?  (Σ w z[s])/Σw : 0) + b  +  (i>0? zb[i-1]:0) + bb )
template<int D>
__global__ void k_gat_h1(const int* __restrict__ rowptr, const int* __restrict__ esrc,
                         const float* __restrict__ z, const float* __restrict__ el,
                         const float* __restrict__ er, const float* __restrict__ b,
                         const float* __restrict__ zb, const float* __restrict__ bb,
                         float* __restrict__ out, int n){
  constexpr int DR = D / 64;
  int lane = threadIdx.x & 63;
  int i = blockIdx.x * (blockDim.x >> 6) + (threadIdx.x >> 6);
  if (i >= n) return;
  int s0 = rowptr[i], s1 = rowptr[i + 1];
  float eri = er[i];
  float m = -INFINITY;
  for (int e = s0 + lane; e < s1; e += 64)
    m = fmaxf(m, lrelu(el[esrc[e]] + eri));
  m = wred_max(m);
  float den = 0.f;
  float acc[DR];
  #pragma unroll
  for (int j = 0; j < DR; j++) acc[j] = 0.f;
  for (int e = s0; e < s1; ++e){
    int s = esrc[e];
    float w = __expf(lrelu(el[s] + eri) - m);
    den += w;
    const float* zs = z + (size_t)s * D;
    #pragma unroll
    for (int j = 0; j < DR; j++) acc[j] += w * zs[j * 64 + lane];
  }
  float inv = (s1 > s0) ? 1.f / den : 0.f;
  float* op = out + (size_t)i * D;
  #pragma unroll
  for (int j = 0; j < DR; j++){
    int c = j * 64 + lane;
    float chain = bb[c];
    if (i > 0) chain += zb[(size_t)(i - 1) * D + c];
    op[c] = 0.5f * ((acc[j] * inv + b[c]) + chain);
  }
}

// ---------------- GAT aggregation, 4 heads x 64 dims ----------------
__global__ void k_gat_mh(const int* __restrict__ rowptr, const int* __restrict__ esrc,
                         const float* __restrict__ z, const float* __restrict__ el,
                         const float* __restrict__ er, const float* __restrict__ b,
                         const float* __restrict__ zb, const float* __restrict__ bb,
                         float* __restrict__ out, int n){
  int lane = threadIdx.x & 63;
  int i = blockIdx.x * (blockDim.x >> 6) + (threadIdx.x >> 6);
  if (i >= n) return;
  int s0 = rowptr[i], s1 = rowptr[i + 1];
  const float4 eri = *(const float4*)(er + (size_t)i * 4);
  float m0 = -INFINITY, m1 = -INFINITY, m2 = -INFINITY, m3 = -INFINITY;
  for (int e = s0 + lane; e < s1; e += 64){
    float4 e4 = *(const float4*)(el + (size_t)esrc[e] * 4);
    m0 = fmaxf(m0, lrelu(e4.x + eri.x));
    m1 = fmaxf(m1, lrelu(e4.y + eri.y));
    m2 = fmaxf(m2, lrelu(e4.z + eri.z));
    m3 = fmaxf(m3, lrelu(e4.w + eri.w));
  }
  m0 = wred_max(m0); m1 = wred_max(m1); m2 = wred_max(m2); m3 = wred_max(m3);
  float d0 = 0.f, d1 = 0.f, d2 = 0.f, d3 = 0.f;
  float a0 = 0.f, a1 = 0.f, a2 = 0.f, a3 = 0.f;
  for (int e = s0; e < s1; ++e){
    int s = esrc[e];
    float4 e4 = *(const float4*)(el + (size_t)s * 4);
    float w0 = __expf(lrelu(e4.x + eri.x) - m0);
    float w1 = __expf(lrelu(e4.y + eri.y) - m1);
    float w2 = __expf(lrelu(e4.z + eri.z) - m2);
    float w3 = __expf(lrelu(e4.w + eri.w) - m3);
    d0 += w0; d1 += w1; d2 += w2; d3 += w3;
    const float* zs = z + (size_t)s * 256;
    a0 += w0 * zs[lane];
    a1 += w1 * zs[64 + lane];
    a2 += w2 * zs[128 + lane];
    a3 += w3 * zs[192 + lane];
  }
  float has = (s1 > s0) ? 1.f : 0.f;
  a0 = (has != 0.f) ? a0 / d0 : 0.f;
  a1 = (has != 0.f) ? a1 / d1 : 0.f;
  a2 = (has != 0.f) ? a2 / d2 : 0.f;
  a3 = (has != 0.f) ? a3 / d3 : 0.f;
  float* op = out + (size_t)i * 256;
  float av[4] = {a0, a1, a2, a3};
  #pragma unroll
  for (int h = 0; h < 4; h++){
    int c = h * 64 + lane;
    float chain = bb[c];
    if (i > 0) chain += zb[(size_t)(i - 1) * 256 + c];
    op[c] = 0.5f * ((av[h] + b[c]) + chain);
  }
}

// ---------------- chain_pass: m_i = h[i-1]-h[i], L2-normalize last dim ----------------
__global__ void k_chainpass64(const float* __restrict__ h, float* __restrict__ dh, int n){
  int lane = threadIdx.x & 63;
  int i = blockIdx.x * (blockDim.x >> 6) + (threadIdx.x >> 6);
  if (i >= n) return;
  float d = 0.f;
  if (i > 0) d = h[(size_t)(i - 1) * 64 + lane] - h[(size_t)i * 64 + lane];
  float ss = wred_sum(d * d);
  dh[(size_t)i * 64 + lane] = d / (sqrtf(ss) + 1e-7f);
}

__global__ void k_chainpass_mh(const float* __restrict__ hm, float* __restrict__ ds, int n){
  int lane = threadIdx.x & 63;
  int i = blockIdx.x * (blockDim.x >> 6) + (threadIdx.x >> 6);
  if (i >= n) return;
  const float* cur = hm + (size_t)i * 256;
  const float* prv = hm + (size_t)(i - 1) * 256;
  #pragma unroll
  for (int h = 0; h < 4; h++){
    int c = h * 64 + lane;
    float d = (i > 0) ? (prv[c] - cur[c]) : 0.f;
    float ss = wred_sum(d * d);
    ds[(size_t)i * 256 + c] = d / (sqrtf(ss) + 1e-7f);
  }
}

// ---------------- column-wise prefix sum over nodes (256 cols) ----------------
__global__ void k_chunk_sum(const float* __restrict__ ds, float* __restrict__ csum, int n, int ch){
  int b = blockIdx.x, t = threadIdx.x;
  int r0 = b * ch, r1 = r0 + ch; if (r1 > n) r1 = n;
  float s = 0.f;
  for (int r = r0; r < r1; r++) s += ds[(size_t)r * 256 + t];
  csum[(size_t)b * 256 + t] = s;
}
__global__ void k_scan_chunks(float* __restrict__ csum, int nb){
  int t = threadIdx.x;
  float run = 0.f;
  for (int b = 0; b < nb; b++){
    float v = csum[(size_t)b * 256 + t];
    csum[(size_t)b * 256 + t] = run;
    run += v;
  }
}
__global__ void k_apply_scan(float* __restrict__ ds, const float* __restrict__ csum, int n, int ch){
  int b = blockIdx.x, t = threadIdx.x;
  int r0 = b * ch, r1 = r0 + ch; if (r1 > n) r1 = n;
  float run = csum[(size_t)b * 256 + t];
  for (int r = r0; r < r1; r++){
    run += ds[(size_t)r * 256 + t];
    ds[(size_t)r * 256 + t] = run;
  }
}

extern "C" void kernel_launch(void* const* d_in, const int* in_sizes, int n_in,
                              void* d_out, int out_size, void* d_ws, size_t ws_size,
                              hipStream_t stream){
  const float* x    = (const float*)d_in[0];
  const int*   src0 = (const int*)d_in[1];
  const int*   dst0 = (const int*)d_in[2];
  // d_in[3]=src1, d_in[4]=dst1: chain graph is arange -> handled analytically.
  const float* W1a  = (const float*)d_in[5];
  const float* al1a = (const float*)d_in[6];
  const float* ar1a = (const float*)d_in[7];
  const float* b1a  = (const float*)d_in[8];
  const float* W1b  = (const float*)d_in[9];
  const float* b1b  = (const float*)d_in[12];
  const float* W2a  = (const float*)d_in[13];
  const float* al2a = (const float*)d_in[14];
  const float* ar2a = (const float*)d_in[15];
  const float* b2a  = (const float*)d_in[16];
  const float* W2b  = (const float*)d_in[17];
  const float* b2b  = (const float*)d_in[20];
  const float* Wma  = (const float*)d_in[21];
  const float* alma = (const float*)d_in[22];
  const float* arma = (const float*)d_in[23];
  const float* bma  = (const float*)d_in[24];
  const float* Wmb  = (const float*)d_in[25];
  const float* bmb  = (const float*)d_in[28];

  const int n = in_sizes[0] / 64;
  const int E = in_sizes[1];
  const size_t nf = (size_t)n;

  // workspace layout (fp32): A,B,C are n*256; D2,E2 are n*64; attention logits; scan; CSR
  float* ws  = (float*)d_ws;
  float* A   = ws;
  float* B   = A + nf * 256;
  float* C   = B + nf * 256;
  float* D2  = C + nf * 256;   // h2 [n,64]
  float* E2  = D2 + nf * 64;   // dh [n,64]
  float* ela = E2 + nf * 64;   // [n,4] (only [n] used for 1-head layers)
  float* era = ela + nf * 4;
  const int ch = 100;
  const int nb = (n + ch - 1) / ch;
  float* csum = era + nf * 4;  // [nb,256]
  int* deg    = (int*)(csum + (size_t)nb * 256);
  int* rowptr = deg + n;
  int* cursor = rowptr + (n + 1);
  int* esrc   = cursor + n;

  float* dsout = (float*)d_out;   // ds staged in d_out, scanned in-place

  const int nwb = (n + 3) / 4;      // 4 waves (nodes) per 256-thread block
  const int ngb = (n + 31) / 32;    // 32 rows per block for GEMM
  const int eb  = (E + 255) / 256;

  // CSR of interacts graph by dst (shared by all three GAT layers)
  hipMemsetAsync(deg, 0, (size_t)n * sizeof(int), stream);
  k_hist<<<eb, 256, 0, stream>>>(dst0, deg, E);
  k_scan_rowptr<<<1, 256, 0, stream>>>(deg, rowptr, n);
  hipMemcpyAsync(cursor, rowptr, (size_t)n * sizeof(int), hipMemcpyDeviceToDevice, stream);
  k_scatter<<<eb, 256, 0, stream>>>(src0, dst0, cursor, esrc, E);

  // layer 1: in=64 -> hid=128
  k_gemm<64, 128, 1><<<ngb, 256, 0, stream>>>(x, W1a, al1a, ar1a, A, ela, era, n);
  k_gemm<64, 128, 0><<<ngb, 256, 0, stream>>>(x, W1b, nullptr, nullptr, B, nullptr, nullptr, n);
  k_gat_h1<128><<<nwb, 256, 0, stream>>>(rowptr, esrc, A, ela, era, b1a, B, b1b, C, n);

  // layer 2: hid=128 -> out=64
  k_gemm<128, 64, 1><<<ngb, 256, 0, stream>>>(C, W2a, al2a, ar2a, A, ela, era, n);
  k_gemm<128, 64, 0><<<ngb, 256, 0, stream>>>(C, W2b, nullptr, nullptr, B, nullptr, nullptr, n);
  k_gat_h1<64><<<nwb, 256, 0, stream>>>(rowptr, esrc, A, ela, era, b2a, B, b2b, D2, n);

  // dh = chain_pass(h2); conh = cumsum over singleton axis = dh
  k_chainpass64<<<nwb, 256, 0, stream>>>(D2, E2, n);

  // MH layer: out=64 -> 4 heads x 64
  k_gemm<64, 256, 4><<<ngb, 256, 0, stream>>>(E2, Wma, alma, arma, A, ela, era, n);
  k_gemm<64, 256, 0><<<ngb, 256, 0, stream>>>(E2, Wmb, nullptr, nullptr, B, nullptr, nullptr, n);
  k_gat_mh<<<nwb, 256, 0, stream>>>(rowptr, esrc, A, ela, era, bma, B, bmb, C, n);

  // ds = chain_pass(hm) -> staged directly in d_out
  k_chainpass_mh<<<nwb, 256, 0, stream>>>(C, dsout, n);

  // res = cumsum(ds, axis=0), in-place in d_out
  k_chunk_sum<<<nb, 256, 0, stream>>>(dsout, csum, n, ch);
  k_scan_chunks<<<1, 256, 0, stream>>>(csum, nb);
  k_apply_scan<<<nb, 256, 0, stream>>>(dsout, csum, n, ch);
}

// Round 4
// 762.893 us; speedup vs baseline: 2.7630x; 1.2750x over previous
//
#include <hip/hip_runtime.h>
#include <math.h>

__device__ __forceinline__ float wred_sum(float v){
  #pragma unroll
  for (int o = 32; o > 0; o >>= 1) v += __shfl_xor(v, o);
  return v;
}
__device__ __forceinline__ float wred_max(float v){
  #pragma unroll
  for (int o = 32; o > 0; o >>= 1) v = fmaxf(v, __shfl_xor(v, o));
  return v;
}
__device__ __forceinline__ float lrelu(float v){ return v > 0.f ? v : 0.2f * v; }

// ---------------- CSR build (dst-sorted) ----------------
__global__ void k_hist(const int* __restrict__ dst, int* __restrict__ deg, int E){
  int t = blockIdx.x * blockDim.x + threadIdx.x;
  if (t < E) atomicAdd(&deg[dst[t]], 1);
}

// per-256-block sums of deg
__global__ void k_deg_bsum(const int* __restrict__ deg, int* __restrict__ bsum, int n){
  __shared__ int s[256];
  int b = blockIdx.x, t = threadIdx.x;
  int i = b * 256 + t;
  s[t] = (i < n) ? deg[i] : 0;
  __syncthreads();
  for (int o = 128; o > 0; o >>= 1){ if (t < o) s[t] += s[t + o]; __syncthreads(); }
  if (t == 0) bsum[b] = s[0];
}
// single-block exclusive scan of bsum (nblk <= 256)
__global__ void k_bsum_scan(int* __restrict__ bsum, int nblk){
  __shared__ int s[256];
  int t = threadIdx.x;
  s[t] = (t < nblk) ? bsum[t] : 0;
  __syncthreads();
  for (int o = 1; o < 256; o <<= 1){
    int add = (t >= o) ? s[t - o] : 0;
    __syncthreads();
    s[t] += add;
    __syncthreads();
  }
  if (t < nblk) bsum[t] = (t > 0) ? s[t - 1] : 0;
}
// rowptr[i] = bsum[b] + exclusive-prefix-in-block; also writes cursor and rowptr[n]
__global__ void k_rowptr(const int* __restrict__ deg, const int* __restrict__ bsum,
                         int* __restrict__ rowptr, int* __restrict__ cursor, int n, int E){
  __shared__ int s[256];
  int b = blockIdx.x, t = threadIdx.x;
  int i = b * 256 + t;
  int v = (i < n) ? deg[i] : 0;
  s[t] = v;
  __syncthreads();
  for (int o = 1; o < 256; o <<= 1){
    int add = (t >= o) ? s[t - o] : 0;
    __syncthreads();
    s[t] += add;
    __syncthreads();
  }
  if (i < n){
    int rp = bsum[b] + s[t] - v;
    rowptr[i] = rp;
    cursor[i] = rp;
    if (i == n - 1) rowptr[n] = E;
  }
}

__global__ void k_scatter(const int* __restrict__ src, const int* __restrict__ dst,
                          int* __restrict__ cursor, int* __restrict__ esrc, int E){
  int t = blockIdx.x * blockDim.x + threadIdx.x;
  if (t < E){
    int d = dst[t];
    int p = atomicAdd(&cursor[d], 1);
    esrc[p] = src[t];
  }
}

// ---------------- GEMM z = x @ W^T (+ el/er attention logits) ----------------
// Block = 256 threads = 4 waves; each wave computes R=8 rows; block = 32 rows.
// W staged transposed in LDS (float4 over k, padded); x rows staged in LDS,
// read at wave-uniform addresses (broadcast). No shfl in the hot loop.
template<int K, int C, int H>
__global__ void k_gemm(const float* __restrict__ x, const float* __restrict__ W,
                       const float* __restrict__ al, const float* __restrict__ ar,
                       float* __restrict__ z, float* __restrict__ el, float* __restrict__ er,
                       int n){
  constexpr int K4 = K / 4;
  constexpr int CR = C / 64;
  constexpr int CP = C + 1;
  constexpr int R = 8;
  constexpr int ROWS = 4 * R;
  __shared__ float4 WQ[K4 * CP];
  __shared__ float  XS[ROWS][K];

  int t = threadIdx.x;
  int lane = t & 63, wv = t >> 6;
  int rowbase = blockIdx.x * ROWS;

  const float4* W4 = (const float4*)W;
  for (int idx = t; idx < C * K4; idx += 256){
    int c = idx / K4, k4 = idx - c * K4;
    WQ[k4 * CP + c] = W4[idx];
  }
  for (int idx = t; idx < ROWS * K; idx += 256){
    int r = idx / K, k = idx - r * K;
    int row = rowbase + r;
    XS[r][k] = (row < n) ? x[(size_t)row * K + k] : 0.f;
  }
  __syncthreads();

  float acc[R][CR];
  #pragma unroll
  for (int r = 0; r < R; r++)
    #pragma unroll
    for (int j = 0; j < CR; j++) acc[r][j] = 0.f;

  const int r0 = wv * R;
  #pragma unroll 4
  for (int k4 = 0; k4 < K4; k4++){
    float4 wq[CR];
    #pragma unroll
    for (int j = 0; j < CR; j++) wq[j] = WQ[k4 * CP + j * 64 + lane];
    #pragma unroll
    for (int r = 0; r < R; r++){
      float4 xk = *(const float4*)&XS[r0 + r][k4 * 4];
      #pragma unroll
      for (int j = 0; j < CR; j++){
        acc[r][j] += xk.x * wq[j].x;
        acc[r][j] += xk.y * wq[j].y;
        acc[r][j] += xk.z * wq[j].z;
        acc[r][j] += xk.w * wq[j].w;
      }
    }
  }

  float alv[CR], arv[CR];
  if constexpr (H > 0){
    #pragma unroll
    for (int j = 0; j < CR; j++){ alv[j] = al[j * 64 + lane]; arv[j] = ar[j * 64 + lane]; }
  }

  #pragma unroll
  for (int r = 0; r < R; r++){
    int row = rowbase + r0 + r;
    if (row >= n) continue;
    float* zr = z + (size_t)row * C;
    #pragma unroll
    for (int j = 0; j < CR; j++) zr[j * 64 + lane] = acc[r][j];
    if constexpr (H == 1){
      float pl = 0.f, pr = 0.f;
      #pragma unroll
      for (int j = 0; j < CR; j++){ pl += acc[r][j] * alv[j]; pr += acc[r][j] * arv[j]; }
      pl = wred_sum(pl); pr = wred_sum(pr);
      if (lane == 0){ el[row] = pl; er[row] = pr; }
    } else if constexpr (H > 1){
      #pragma unroll
      for (int j = 0; j < CR; j++){
        float pl = wred_sum(acc[r][j] * alv[j]);
        float pr = wred_sum(acc[r][j] * arv[j]);
        if (lane == 0){ el[(size_t)row * H + j] = pl; er[(size_t)row * H + j] = pr; }
      }
    }
  }
}

// ---------------- GAT aggregation, 1 head, fused with chain-shift + mean ----------------
template<int D>
__global__ void k_gat_h1(const int* __restrict__ rowptr, const int* __restrict__ esrc,
                         const float* __restrict__ z, const float* __restrict__ el,
                         const float* __restrict__ er, const float* __restrict__ b,
                         const float* __restrict__ zb, const float* __restrict__ bb,
                         float* __restrict__ out, int n){
  constexpr int DR = D / 64;
  int lane = threadIdx.x & 63;
  int i = blockIdx.x * (blockDim.x >> 6) + (threadIdx.x >> 6);
  if (i >= n) return;
  int s0 = rowptr[i], s1 = rowptr[i + 1];
  float eri = er[i];
  float m = -INFINITY;
  for (int e = s0 + lane; e < s1; e += 64)
    m = fmaxf(m, lrelu(el[esrc[e]] + eri));
  m = wred_max(m);
  float den = 0.f, den2 = 0.f;
  float acc[DR], acc2[DR];
  #pragma unroll
  for (int j = 0; j < DR; j++){ acc[j] = 0.f; acc2[j] = 0.f; }
  int e = s0;
  for (; e + 1 < s1; e += 2){
    int sA = esrc[e], sB = esrc[e + 1];
    float wA = __expf(lrelu(el[sA] + eri) - m);
    float wB = __expf(lrelu(el[sB] + eri) - m);
    den += wA; den2 += wB;
    const float* zA = z + (size_t)sA * D;
    const float* zB = z + (size_t)sB * D;
    #pragma unroll
    for (int j = 0; j < DR; j++){
      acc[j]  += wA * zA[j * 64 + lane];
      acc2[j] += wB * zB[j * 64 + lane];
    }
  }
  if (e < s1){
    int sA = esrc[e];
    float wA = __expf(lrelu(el[sA] + eri) - m);
    den += wA;
    const float* zA = z + (size_t)sA * D;
    #pragma unroll
    for (int j = 0; j < DR; j++) acc[j] += wA * zA[j * 64 + lane];
  }
  den += den2;
  float inv = (s1 > s0) ? 1.f / den : 0.f;
  float* op = out + (size_t)i * D;
  #pragma unroll
  for (int j = 0; j < DR; j++){
    int c = j * 64 + lane;
    float chain = bb[c];
    if (i > 0) chain += zb[(size_t)(i - 1) * D + c];
    op[c] = 0.5f * (((acc[j] + acc2[j]) * inv + b[c]) + chain);
  }
}

// ---------------- GAT aggregation, 4 heads x 64 dims ----------------
__global__ void k_gat_mh(const int* __restrict__ rowptr, const int* __restrict__ esrc,
                         const float* __restrict__ z, const float* __restrict__ el,
                         const float* __restrict__ er, const float* __restrict__ b,
                         const float* __restrict__ zb, const float* __restrict__ bb,
                         float* __restrict__ out, int n){
  int lane = threadIdx.x & 63;
  int i = blockIdx.x * (blockDim.x >> 6) + (threadIdx.x >> 6);
  if (i >= n) return;
  int s0 = rowptr[i], s1 = rowptr[i + 1];
  const float4 eri = *(const float4*)(er + (size_t)i * 4);
  float m0 = -INFINITY, m1 = -INFINITY, m2 = -INFINITY, m3 = -INFINITY;
  for (int e = s0 + lane; e < s1; e += 64){
    float4 e4 = *(const float4*)(el + (size_t)esrc[e] * 4);
    m0 = fmaxf(m0, lrelu(e4.x + eri.x));
    m1 = fmaxf(m1, lrelu(e4.y + eri.y));
    m2 = fmaxf(m2, lrelu(e4.z + eri.z));
    m3 = fmaxf(m3, lrelu(e4.w + eri.w));
  }
  m0 = wred_max(m0); m1 = wred_max(m1); m2 = wred_max(m2); m3 = wred_max(m3);
  float d0 = 0.f, d1 = 0.f, d2 = 0.f, d3 = 0.f;
  float a0 = 0.f, a1 = 0.f, a2 = 0.f, a3 = 0.f;
  float d0B = 0.f, d1B = 0.f, d2B = 0.f, d3B = 0.f;
  float a0B = 0.f, a1B = 0.f, a2B = 0.f, a3B = 0.f;
  int e = s0;
  for (; e + 1 < s1; e += 2){
    int sA = esrc[e], sB = esrc[e + 1];
    float4 eA = *(const float4*)(el + (size_t)sA * 4);
    float4 eB = *(const float4*)(el + (size_t)sB * 4);
    const float* zA = z + (size_t)sA * 256;
    const float* zB = z + (size_t)sB * 256;
    float w0 = __expf(lrelu(eA.x + eri.x) - m0);
    float w1 = __expf(lrelu(eA.y + eri.y) - m1);
    float w2 = __expf(lrelu(eA.z + eri.z) - m2);
    float w3 = __expf(lrelu(eA.w + eri.w) - m3);
    float v0 = __expf(lrelu(eB.x + eri.x) - m0);
    float v1 = __expf(lrelu(eB.y + eri.y) - m1);
    float v2 = __expf(lrelu(eB.z + eri.z) - m2);
    float v3 = __expf(lrelu(eB.w + eri.w) - m3);
    d0 += w0; d1 += w1; d2 += w2; d3 += w3;
    d0B += v0; d1B += v1; d2B += v2; d3B += v3;
    a0 += w0 * zA[lane];        a0B += v0 * zB[lane];
    a1 += w1 * zA[64 + lane];   a1B += v1 * zB[64 + lane];
    a2 += w2 * zA[128 + lane];  a2B += v2 * zB[128 + lane];
    a3 += w3 * zA[192 + lane];  a3B += v3 * zB[192 + lane];
  }
  if (e < s1){
    int sA = esrc[e];
    float4 eA = *(const float4*)(el + (size_t)sA * 4);
    const float* zA = z + (size_t)sA * 256;
    float w0 = __expf(lrelu(eA.x + eri.x) - m0);
    float w1 = __expf(lrelu(eA.y + eri.y) - m1);
    float w2 = __expf(lrelu(eA.z + eri.z) - m2);
    float w3 = __expf(lrelu(eA.w + eri.w) - m3);
    d0 += w0; d1 += w1; d2 += w2; d3 += w3;
    a0 += w0 * zA[lane];
    a1 += w1 * zA[64 + lane];
    a2 += w2 * zA[128 + lane];
    a3 += w3 * zA[192 + lane];
  }
  d0 += d0B; d1 += d1B; d2 += d2B; d3 += d3B;
  a0 += a0B; a1 += a1B; a2 += a2B; a3 += a3B;
  float has = (s1 > s0) ? 1.f : 0.f;
  a0 = (has != 0.f) ? a0 / d0 : 0.f;
  a1 = (has != 0.f) ? a1 / d1 : 0.f;
  a2 = (has != 0.f) ? a2 / d2 : 0.f;
  a3 = (has != 0.f) ? a3 / d3 : 0.f;
  float* op = out + (size_t)i * 256;
  float av[4] = {a0, a1, a2, a3};
  #pragma unroll
  for (int h = 0; h < 4; h++){
    int c = h * 64 + lane;
    float chain = bb[c];
    if (i > 0) chain += zb[(size_t)(i - 1) * 256 + c];
    op[c] = 0.5f * ((av[h] + b[c]) + chain);
  }
}

// ---------------- chain_pass: m_i = h[i-1]-h[i], L2-normalize last dim ----------------
__global__ void k_chainpass64(const float* __restrict__ h, float* __restrict__ dh, int n){
  int lane = threadIdx.x & 63;
  int i = blockIdx.x * (blockDim.x >> 6) + (threadIdx.x >> 6);
  if (i >= n) return;
  float d = 0.f;
  if (i > 0) d = h[(size_t)(i - 1) * 64 + lane] - h[(size_t)i * 64 + lane];
  float ss = wred_sum(d * d);
  dh[(size_t)i * 64 + lane] = d / (sqrtf(ss) + 1e-7f);
}

__global__ void k_chainpass_mh(const float* __restrict__ hm, float* __restrict__ ds, int n){
  int lane = threadIdx.x & 63;
  int i = blockIdx.x * (blockDim.x >> 6) + (threadIdx.x >> 6);
  if (i >= n) return;
  const float* cur = hm + (size_t)i * 256;
  const float* prv = hm + (size_t)(i - 1) * 256;
  #pragma unroll
  for (int h = 0; h < 4; h++){
    int c = h * 64 + lane;
    float d = (i > 0) ? (prv[c] - cur[c]) : 0.f;
    float ss = wred_sum(d * d);
    ds[(size_t)i * 256 + c] = d / (sqrtf(ss) + 1e-7f);
  }
}

// ---------------- column-wise prefix sum over nodes (256 cols) ----------------
__global__ void k_chunk_sum(const float* __restrict__ ds, float* __restrict__ csum, int n, int ch){
  int b = blockIdx.x, t = threadIdx.x;
  int r0 = b * ch, r1 = r0 + ch; if (r1 > n) r1 = n;
  float s = 0.f;
  for (int r = r0; r < r1; r++) s += ds[(size_t)r * 256 + t];
  csum[(size_t)b * 256 + t] = s;
}
// parallel exclusive scan of csum along chunks: one block per column (nb <= 512)
__global__ void k_scan_chunks_par(float* __restrict__ csum, int nb){
  __shared__ float s[512];
  int col = blockIdx.x;
  int t = threadIdx.x;
  s[t] = (t < nb) ? csum[(size_t)t * 256 + col] : 0.f;
  __syncthreads();
  #pragma unroll
  for (int o = 1; o < 512; o <<= 1){
    float add = (t >= o) ? s[t - o] : 0.f;
    __syncthreads();
    s[t] += add;
    __syncthreads();
  }
  if (t < nb) csum[(size_t)t * 256 + col] = (t > 0) ? s[t - 1] : 0.f;
}
__global__ void k_apply_scan(float* __restrict__ ds, const float* __restrict__ csum, int n, int ch){
  int b = blockIdx.x, t = threadIdx.x;
  int r0 = b * ch, r1 = r0 + ch; if (r1 > n) r1 = n;
  float run = csum[(size_t)b * 256 + t];
  for (int r = r0; r < r1; r++){
    run += ds[(size_t)r * 256 + t];
    ds[(size_t)r * 256 + t] = run;
  }
}

extern "C" void kernel_launch(void* const* d_in, const int* in_sizes, int n_in,
                              void* d_out, int out_size, void* d_ws, size_t ws_size,
                              hipStream_t stream){
  const float* x    = (const float*)d_in[0];
  const int*   src0 = (const int*)d_in[1];
  const int*   dst0 = (const int*)d_in[2];
  const float* W1a  = (const float*)d_in[5];
  const float* al1a = (const float*)d_in[6];
  const float* ar1a = (const float*)d_in[7];
  const float* b1a  = (const float*)d_in[8];
  const float* W1b  = (const float*)d_in[9];
  const float* b1b  = (const float*)d_in[12];
  const float* W2a  = (const float*)d_in[13];
  const float* al2a = (const float*)d_in[14];
  const float* ar2a = (const float*)d_in[15];
  const float* b2a  = (const float*)d_in[16];
  const float* W2b  = (const float*)d_in[17];
  const float* b2b  = (const float*)d_in[20];
  const float* Wma  = (const float*)d_in[21];
  const float* alma = (const float*)d_in[22];
  const float* arma = (const float*)d_in[23];
  const float* bma  = (const float*)d_in[24];
  const float* Wmb  = (const float*)d_in[25];
  const float* bmb  = (const float*)d_in[28];

  const int n = in_sizes[0] / 64;
  const int E = in_sizes[1];
  const size_t nf = (size_t)n;

  float* ws  = (float*)d_ws;
  float* A   = ws;
  float* B   = A + nf * 256;
  float* C   = B + nf * 256;
  float* D2  = C + nf * 256;   // h2 [n,64]
  float* E2  = D2 + nf * 64;   // dh [n,64]
  float* ela = E2 + nf * 64;   // [n,4]
  float* era = ela + nf * 4;
  const int ch = 100;
  const int nb = (n + ch - 1) / ch;      // 500 <= 512
  float* csum = era + nf * 4;  // [nb,256]
  int* deg    = (int*)(csum + (size_t)nb * 256);
  int* rowptr = deg + n;
  int* cursor = rowptr + (n + 1);
  int* esrc   = cursor + n;
  int* bsum   = esrc + E;

  float* dsout = (float*)d_out;

  const int nwb  = (n + 3) / 4;       // 4 waves (nodes) per 256-thread block
  const int ngb  = (n + 31) / 32;     // 32 rows per block for GEMM
  const int eb   = (E + 255) / 256;
  const int nblk = (n + 255) / 256;   // <= 256

  // CSR of interacts graph by dst (shared by all three GAT layers)
  hipMemsetAsync(deg, 0, (size_t)n * sizeof(int), stream);
  k_hist<<<eb, 256, 0, stream>>>(dst0, deg, E);
  k_deg_bsum<<<nblk, 256, 0, stream>>>(deg, bsum, n);
  k_bsum_scan<<<1, 256, 0, stream>>>(bsum, nblk);
  k_rowptr<<<nblk, 256, 0, stream>>>(deg, bsum, rowptr, cursor, n, E);
  k_scatter<<<eb, 256, 0, stream>>>(src0, dst0, cursor, esrc, E);

  // layer 1: in=64 -> hid=128
  k_gemm<64, 128, 1><<<ngb, 256, 0, stream>>>(x, W1a, al1a, ar1a, A, ela, era, n);
  k_gemm<64, 128, 0><<<ngb, 256, 0, stream>>>(x, W1b, nullptr, nullptr, B, nullptr, nullptr, n);
  k_gat_h1<128><<<nwb, 256, 0, stream>>>(rowptr, esrc, A, ela, era, b1a, B, b1b, C, n);

  // layer 2: hid=128 -> out=64
  k_gemm<128, 64, 1><<<ngb, 256, 0, stream>>>(C, W2a, al2a, ar2a, A, ela, era, n);
  k_gemm<128, 64, 0><<<ngb, 256, 0, stream>>>(C, W2b, nullptr, nullptr, B, nullptr, nullptr, n);
  k_gat_h1<64><<<nwb, 256, 0, stream>>>(rowptr, esrc, A, ela, era, b2a, B, b2b, D2, n);

  // dh = chain_pass(h2); conh = cumsum over singleton axis = dh
  k_chainpass64<<<nwb, 256, 0, stream>>>(D2, E2, n);

  // MH layer: out=64 -> 4 heads x 64
  k_gemm<64, 256, 4><<<ngb, 256, 0, stream>>>(E2, Wma, alma, arma, A, ela, era, n);
  k_gemm<64, 256, 0><<<ngb, 256, 0, stream>>>(E2, Wmb, nullptr, nullptr, B, nullptr, nullptr, n);
  k_gat_mh<<<nwb, 256, 0, stream>>>(rowptr, esrc, A, ela, era, bma, B, bmb, C, n);

  // ds = chain_pass(hm) -> staged directly in d_out
  k_chainpass_mh<<<nwb, 256, 0, stream>>>(C, dsout, n);

  // res = cumsum(ds, axis=0), in-place in d_out
  k_chunk_sum<<<nb, 256, 0, stream>>>(dsout, csum, n, ch);
  k_scan_chunks_par<<<256, 512, 0, stream>>>(csum, nb);
  k_apply_scan<<<nb, 256, 0, stream>>>(dsout, csum, n, ch);
}

// Round 5
// 718.152 us; speedup vs baseline: 2.9352x; 1.0623x over previous
//
#include <hip/hip_runtime.h>
#include <math.h>

__device__ __forceinline__ float wred_sum(float v){
  #pragma unroll
  for (int o = 32; o > 0; o >>= 1) v += __shfl_xor(v, o);
  return v;
}
__device__ __forceinline__ float wred_max(float v){
  #pragma unroll
  for (int o = 32; o > 0; o >>= 1) v = fmaxf(v, __shfl_xor(v, o));
  return v;
}
__device__ __forceinline__ float lrelu(float v){ return v > 0.f ? v : 0.2f * v; }

// ---------------- CSR build (dst-sorted) ----------------
__global__ void k_hist(const int* __restrict__ dst, int* __restrict__ deg, int E){
  int t = blockIdx.x * blockDim.x + threadIdx.x;
  if (t < E) atomicAdd(&deg[dst[t]], 1);
}

__global__ void k_deg_bsum(const int* __restrict__ deg, int* __restrict__ bsum, int n){
  __shared__ int s[256];
  int b = blockIdx.x, t = threadIdx.x;
  int i = b * 256 + t;
  s[t] = (i < n) ? deg[i] : 0;
  __syncthreads();
  for (int o = 128; o > 0; o >>= 1){ if (t < o) s[t] += s[t + o]; __syncthreads(); }
  if (t == 0) bsum[b] = s[0];
}
__global__ void k_bsum_scan(int* __restrict__ bsum, int nblk){
  __shared__ int s[256];
  int t = threadIdx.x;
  s[t] = (t < nblk) ? bsum[t] : 0;
  __syncthreads();
  for (int o = 1; o < 256; o <<= 1){
    int add = (t >= o) ? s[t - o] : 0;
    __syncthreads();
    s[t] += add;
    __syncthreads();
  }
  if (t < nblk) bsum[t] = (t > 0) ? s[t - 1] : 0;
}
__global__ void k_rowptr(const int* __restrict__ deg, const int* __restrict__ bsum,
                         int* __restrict__ rowptr, int* __restrict__ cursor, int n, int E){
  __shared__ int s[256];
  int b = blockIdx.x, t = threadIdx.x;
  int i = b * 256 + t;
  int v = (i < n) ? deg[i] : 0;
  s[t] = v;
  __syncthreads();
  for (int o = 1; o < 256; o <<= 1){
    int add = (t >= o) ? s[t - o] : 0;
    __syncthreads();
    s[t] += add;
    __syncthreads();
  }
  if (i < n){
    int rp = bsum[b] + s[t] - v;
    rowptr[i] = rp;
    cursor[i] = rp;
    if (i == n - 1) rowptr[n] = E;
  }
}

__global__ void k_scatter(const int* __restrict__ src, const int* __restrict__ dst,
                          int* __restrict__ cursor, int* __restrict__ esrc, int E){
  int t = blockIdx.x * blockDim.x + threadIdx.x;
  if (t < E){
    int d = dst[t];
    int p = atomicAdd(&cursor[d], 1);
    esrc[p] = src[t];
  }
}

// ---------------- attention-logit weight precompute: vv = W^T {al, ar} ----------------
// el[i] = z[i]·al = x[i]·(W^T al)  -- so logits become 2H extra GEMM columns.
__global__ void k_valvar_all(const float* __restrict__ W1, const float* __restrict__ al1, const float* __restrict__ ar1,
                             const float* __restrict__ W2, const float* __restrict__ al2, const float* __restrict__ ar2,
                             const float* __restrict__ Wm, const float* __restrict__ alm, const float* __restrict__ arm,
                             float* __restrict__ vv1, float* __restrict__ vv2, float* __restrict__ vvm){
  int b = blockIdx.x, k = threadIdx.x;
  if (b == 0){
    if (k < 64){ // L1: K=64, C=128, H=1
      float v = 0.f, w = 0.f;
      for (int c = 0; c < 128; c++){ float ww = W1[c * 64 + k]; v += al1[c] * ww; w += ar1[c] * ww; }
      vv1[k] = v; vv1[64 + k] = w;
    }
  } else if (b == 1){ // L2: K=128, C=64, H=1
    float v = 0.f, w = 0.f;
    for (int c = 0; c < 64; c++){ float ww = W2[c * 128 + k]; v += al2[c] * ww; w += ar2[c] * ww; }
    vv2[k] = v; vv2[128 + k] = w;
  } else {
    if (k < 64){ // MH: K=64, C=256, H=4
      for (int h = 0; h < 4; h++){
        float v = 0.f, w = 0.f;
        for (int c = 0; c < 64; c++){
          float ww = Wm[(size_t)(h * 64 + c) * 64 + k];
          v += alm[h * 64 + c] * ww; w += arm[h * 64 + c] * ww;
        }
        vvm[(2 * h) * 64 + k] = v; vvm[(2 * h + 1) * 64 + k] = w;
      }
    }
  }
}

// ---------------- fused dual GEMM: za = x Wa^T, zb = x Wb^T, el/er = x vv ----------------
// 256 thr = 4 waves; ROWS rows/block (XS = 16 KB); W staged in 64-col x 64-k chunks
// (WQ[16][65] float4 -> conflict-free ds_read_b128); lane = col-in-chunk.
template<int K, int C, int H>
__global__ void k_gemm2(const float* __restrict__ x,
                        const float* __restrict__ Wa, const float* __restrict__ Wb,
                        const float* __restrict__ vv,
                        float* __restrict__ za, float* __restrict__ zb,
                        float* __restrict__ el, float* __restrict__ er, int n){
  constexpr int K4 = K / 4, NKC = K / 64, NCC = C / 64;
  constexpr int ROWS = 16384 / (K * 4);
  constexpr int RPW = ROWS / 4;
  __shared__ float  XS[ROWS][K];
  __shared__ float4 WQ[16 * 65];

  int t = threadIdx.x, lane = t & 63, wv = t >> 6;
  int rowbase = blockIdx.x * ROWS;

  for (int idx = t; idx < 1024; idx += 256){
    int r = idx / K4, k4 = idx - r * K4;
    int row = rowbase + r;
    float4 v = make_float4(0.f, 0.f, 0.f, 0.f);
    if (row < n) v = *(const float4*)&x[(size_t)row * K + k4 * 4];
    *(float4*)&XS[r][k4 * 4] = v;
  }

  const int r0 = wv * RPW;
  float acc[RPW];

  for (int m = 0; m < 2; m++){
    const float* W = m ? Wb : Wa;
    float* z = m ? zb : za;
    for (int cc = 0; cc < NCC; cc++){
      #pragma unroll
      for (int r = 0; r < RPW; r++) acc[r] = 0.f;
      for (int kc = 0; kc < NKC; kc++){
        __syncthreads();
        const float4* W4 = (const float4*)W;
        for (int idx = t; idx < 1024; idx += 256){
          int c = idx >> 4, k4 = idx & 15;
          WQ[k4 * 65 + c] = W4[(size_t)(cc * 64 + c) * K4 + kc * 16 + k4];
        }
        __syncthreads();
        #pragma unroll 4
        for (int k4 = 0; k4 < 16; k4++){
          float4 wq = WQ[k4 * 65 + lane];
          #pragma unroll
          for (int r = 0; r < RPW; r++){
            float4 xk = *(const float4*)&XS[r0 + r][kc * 64 + k4 * 4];
            acc[r] += xk.x * wq.x + xk.y * wq.y + xk.z * wq.z + xk.w * wq.w;
          }
        }
      }
      #pragma unroll
      for (int r = 0; r < RPW; r++){
        int row = rowbase + r0 + r;
        if (row < n) z[(size_t)row * C + cc * 64 + lane] = acc[r];
      }
    }
  }

  // ext chunk: cols 0..2H-1 are vv rows -> el/er
  {
    #pragma unroll
    for (int r = 0; r < RPW; r++) acc[r] = 0.f;
    for (int kc = 0; kc < NKC; kc++){
      __syncthreads();
      const float4* V4 = (const float4*)vv;
      for (int idx = t; idx < 1024; idx += 256){
        int c = idx >> 4, k4 = idx & 15;
        float4 v = make_float4(0.f, 0.f, 0.f, 0.f);
        if (c < 2 * H) v = V4[(size_t)c * K4 + kc * 16 + k4];
        WQ[k4 * 65 + c] = v;
      }
      __syncthreads();
      #pragma unroll 4
      for (int k4 = 0; k4 < 16; k4++){
        float4 wq = WQ[k4 * 65 + lane];
        #pragma unroll
        for (int r = 0; r < RPW; r++){
          float4 xk = *(const float4*)&XS[r0 + r][kc * 64 + k4 * 4];
          acc[r] += xk.x * wq.x + xk.y * wq.y + xk.z * wq.z + xk.w * wq.w;
        }
      }
    }
    if (lane < 2 * H){
      int h = lane >> 1;
      float* dst = (lane & 1) ? er : el;
      #pragma unroll
      for (int r = 0; r < RPW; r++){
        int row = rowbase + r0 + r;
        if (row < n) dst[(size_t)row * H + h] = acc[r];
      }
    }
  }
}

// ---------------- GAT aggregation, 1 head, fused with chain-shift + mean ----------------
template<int D>
__global__ void k_gat_h1(const int* __restrict__ rowptr, const int* __restrict__ esrc,
                         const float* __restrict__ z, const float* __restrict__ el,
                         const float* __restrict__ er, const float* __restrict__ b,
                         const float* __restrict__ zb, const float* __restrict__ bb,
                         float* __restrict__ out, int n){
  constexpr int DR = D / 64;
  int lane = threadIdx.x & 63;
  int i = blockIdx.x * (blockDim.x >> 6) + (threadIdx.x >> 6);
  if (i >= n) return;
  int s0 = rowptr[i], s1 = rowptr[i + 1];
  float eri = er[i];
  float m = -INFINITY;
  for (int e = s0 + lane; e < s1; e += 64)
    m = fmaxf(m, lrelu(el[esrc[e]] + eri));
  m = wred_max(m);
  float den = 0.f, den2 = 0.f;
  float acc[DR], acc2[DR];
  #pragma unroll
  for (int j = 0; j < DR; j++){ acc[j] = 0.f; acc2[j] = 0.f; }
  int e = s0;
  for (; e + 1 < s1; e += 2){
    int sA = esrc[e], sB = esrc[e + 1];
    float wA = __expf(lrelu(el[sA] + eri) - m);
    float wB = __expf(lrelu(el[sB] + eri) - m);
    den += wA; den2 += wB;
    const float* zA = z + (size_t)sA * D;
    const float* zB = z + (size_t)sB * D;
    #pragma unroll
    for (int j = 0; j < DR; j++){
      acc[j]  += wA * zA[j * 64 + lane];
      acc2[j] += wB * zB[j * 64 + lane];
    }
  }
  if (e < s1){
    int sA = esrc[e];
    float wA = __expf(lrelu(el[sA] + eri) - m);
    den += wA;
    const float* zA = z + (size_t)sA * D;
    #pragma unroll
    for (int j = 0; j < DR; j++) acc[j] += wA * zA[j * 64 + lane];
  }
  den += den2;
  float inv = (s1 > s0) ? 1.f / den : 0.f;
  float* op = out + (size_t)i * D;
  #pragma unroll
  for (int j = 0; j < DR; j++){
    int c = j * 64 + lane;
    float chain = bb[c];
    if (i > 0) chain += zb[(size_t)(i - 1) * D + c];
    op[c] = 0.5f * (((acc[j] + acc2[j]) * inv + b[c]) + chain);
  }
}

// ---------------- GAT aggregation, 4 heads x 64 dims ----------------
__global__ void k_gat_mh(const int* __restrict__ rowptr, const int* __restrict__ esrc,
                         const float* __restrict__ z, const float* __restrict__ el,
                         const float* __restrict__ er, const float* __restrict__ b,
                         const float* __restrict__ zb, const float* __restrict__ bb,
                         float* __restrict__ out, int n){
  int lane = threadIdx.x & 63;
  int i = blockIdx.x * (blockDim.x >> 6) + (threadIdx.x >> 6);
  if (i >= n) return;
  int s0 = rowptr[i], s1 = rowptr[i + 1];
  const float4 eri = *(const float4*)(er + (size_t)i * 4);
  float m0 = -INFINITY, m1 = -INFINITY, m2 = -INFINITY, m3 = -INFINITY;
  for (int e = s0 + lane; e < s1; e += 64){
    float4 e4 = *(const float4*)(el + (size_t)esrc[e] * 4);
    m0 = fmaxf(m0, lrelu(e4.x + eri.x));
    m1 = fmaxf(m1, lrelu(e4.y + eri.y));
    m2 = fmaxf(m2, lrelu(e4.z + eri.z));
    m3 = fmaxf(m3, lrelu(e4.w + eri.w));
  }
  m0 = wred_max(m0); m1 = wred_max(m1); m2 = wred_max(m2); m3 = wred_max(m3);
  float d0 = 0.f, d1 = 0.f, d2 = 0.f, d3 = 0.f;
  float a0 = 0.f, a1 = 0.f, a2 = 0.f, a3 = 0.f;
  float d0B = 0.f, d1B = 0.f, d2B = 0.f, d3B = 0.f;
  float a0B = 0.f, a1B = 0.f, a2B = 0.f, a3B = 0.f;
  int e = s0;
  for (; e + 1 < s1; e += 2){
    int sA = esrc[e], sB = esrc[e + 1];
    float4 eA = *(const float4*)(el + (size_t)sA * 4);
    float4 eB = *(const float4*)(el + (size_t)sB * 4);
    const float* zA = z + (size_t)sA * 256;
    const float* zB = z + (size_t)sB * 256;
    float w0 = __expf(lrelu(eA.x + eri.x) - m0);
    float w1 = __expf(lrelu(eA.y + eri.y) - m1);
    float w2 = __expf(lrelu(eA.z + eri.z) - m2);
    float w3 = __expf(lrelu(eA.w + eri.w) - m3);
    float v0 = __expf(lrelu(eB.x + eri.x) - m0);
    float v1 = __expf(lrelu(eB.y + eri.y) - m1);
    float v2 = __expf(lrelu(eB.z + eri.z) - m2);
    float v3 = __expf(lrelu(eB.w + eri.w) - m3);
    d0 += w0; d1 += w1; d2 += w2; d3 += w3;
    d0B += v0; d1B += v1; d2B += v2; d3B += v3;
    a0 += w0 * zA[lane];        a0B += v0 * zB[lane];
    a1 += w1 * zA[64 + lane];   a1B += v1 * zB[64 + lane];
    a2 += w2 * zA[128 + lane];  a2B += v2 * zB[128 + lane];
    a3 += w3 * zA[192 + lane];  a3B += v3 * zB[192 + lane];
  }
  if (e < s1){
    int sA = esrc[e];
    float4 eA = *(const float4*)(el + (size_t)sA * 4);
    const float* zA = z + (size_t)sA * 256;
    float w0 = __expf(lrelu(eA.x + eri.x) - m0);
    float w1 = __expf(lrelu(eA.y + eri.y) - m1);
    float w2 = __expf(lrelu(eA.z + eri.z) - m2);
    float w3 = __expf(lrelu(eA.w + eri.w) - m3);
    d0 += w0; d1 += w1; d2 += w2; d3 += w3;
    a0 += w0 * zA[lane];
    a1 += w1 * zA[64 + lane];
    a2 += w2 * zA[128 + lane];
    a3 += w3 * zA[192 + lane];
  }
  d0 += d0B; d1 += d1B; d2 += d2B; d3 += d3B;
  a0 += a0B; a1 += a1B; a2 += a2B; a3 += a3B;
  float has = (s1 > s0) ? 1.f : 0.f;
  a0 = (has != 0.f) ? a0 / d0 : 0.f;
  a1 = (has != 0.f) ? a1 / d1 : 0.f;
  a2 = (has != 0.f) ? a2 / d2 : 0.f;
  a3 = (has != 0.f) ? a3 / d3 : 0.f;
  float* op = out + (size_t)i * 256;
  float av[4] = {a0, a1, a2, a3};
  #pragma unroll
  for (int h = 0; h < 4; h++){
    int c = h * 64 + lane;
    float chain = bb[c];
    if (i > 0) chain += zb[(size_t)(i - 1) * 256 + c];
    op[c] = 0.5f * ((av[h] + b[c]) + chain);
  }
}

// ---------------- chain_pass ----------------
__global__ void k_chainpass64(const float* __restrict__ h, float* __restrict__ dh, int n){
  int lane = threadIdx.x & 63;
  int i = blockIdx.x * (blockDim.x >> 6) + (threadIdx.x >> 6);
  if (i >= n) return;
  float d = 0.f;
  if (i > 0) d = h[(size_t)(i - 1) * 64 + lane] - h[(size_t)i * 64 + lane];
  float ss = wred_sum(d * d);
  dh[(size_t)i * 64 + lane] = d / (sqrtf(ss) + 1e-7f);
}

__global__ void k_chainpass_mh(const float* __restrict__ hm, float* __restrict__ ds, int n){
  int lane = threadIdx.x & 63;
  int i = blockIdx.x * (blockDim.x >> 6) + (threadIdx.x >> 6);
  if (i >= n) return;
  const float* cur = hm + (size_t)i * 256;
  const float* prv = hm + (size_t)(i - 1) * 256;
  #pragma unroll
  for (int h = 0; h < 4; h++){
    int c = h * 64 + lane;
    float d = (i > 0) ? (prv[c] - cur[c]) : 0.f;
    float ss = wred_sum(d * d);
    ds[(size_t)i * 256 + c] = d / (sqrtf(ss) + 1e-7f);
  }
}

// ---------------- column-wise prefix sum over nodes (256 cols) ----------------
__global__ void k_chunk_sum(const float* __restrict__ ds, float* __restrict__ csum, int n, int ch){
  int b = blockIdx.x, t = threadIdx.x;
  int r0 = b * ch, r1 = r0 + ch; if (r1 > n) r1 = n;
  float s = 0.f;
  for (int r = r0; r < r1; r++) s += ds[(size_t)r * 256 + t];
  csum[(size_t)b * 256 + t] = s;
}
__global__ void k_scan_chunks_par(float* __restrict__ csum, int nb){
  __shared__ float s[512];
  int col = blockIdx.x;
  int t = threadIdx.x;
  s[t] = (t < nb) ? csum[(size_t)t * 256 + col] : 0.f;
  __syncthreads();
  #pragma unroll
  for (int o = 1; o < 512; o <<= 1){
    float add = (t >= o) ? s[t - o] : 0.f;
    __syncthreads();
    s[t] += add;
    __syncthreads();
  }
  if (t < nb) csum[(size_t)t * 256 + col] = (t > 0) ? s[t - 1] : 0.f;
}
__global__ void k_apply_scan(float* __restrict__ ds, const float* __restrict__ csum, int n, int ch){
  int b = blockIdx.x, t = threadIdx.x;
  int r0 = b * ch, r1 = r0 + ch; if (r1 > n) r1 = n;
  float run = csum[(size_t)b * 256 + t];
  for (int r = r0; r < r1; r++){
    run += ds[(size_t)r * 256 + t];
    ds[(size_t)r * 256 + t] = run;
  }
}

extern "C" void kernel_launch(void* const* d_in, const int* in_sizes, int n_in,
                              void* d_out, int out_size, void* d_ws, size_t ws_size,
                              hipStream_t stream){
  const float* x    = (const float*)d_in[0];
  const int*   src0 = (const int*)d_in[1];
  const int*   dst0 = (const int*)d_in[2];
  const float* W1a  = (const float*)d_in[5];
  const float* al1a = (const float*)d_in[6];
  const float* ar1a = (const float*)d_in[7];
  const float* b1a  = (const float*)d_in[8];
  const float* W1b  = (const float*)d_in[9];
  const float* b1b  = (const float*)d_in[12];
  const float* W2a  = (const float*)d_in[13];
  const float* al2a = (const float*)d_in[14];
  const float* ar2a = (const float*)d_in[15];
  const float* b2a  = (const float*)d_in[16];
  const float* W2b  = (const float*)d_in[17];
  const float* b2b  = (const float*)d_in[20];
  const float* Wma  = (const float*)d_in[21];
  const float* alma = (const float*)d_in[22];
  const float* arma = (const float*)d_in[23];
  const float* bma  = (const float*)d_in[24];
  const float* Wmb  = (const float*)d_in[25];
  const float* bmb  = (const float*)d_in[28];

  const int n = in_sizes[0] / 64;
  const int E = in_sizes[1];
  const size_t nf = (size_t)n;

  float* ws  = (float*)d_ws;
  float* A   = ws;
  float* B   = A + nf * 256;
  float* C   = B + nf * 256;
  float* D2  = C + nf * 256;   // h2 [n,64]
  float* E2  = D2 + nf * 64;   // dh [n,64]
  float* ela = E2 + nf * 64;   // [n,4]
  float* era = ela + nf * 4;
  const int ch = 100;
  const int nb = (n + ch - 1) / ch;      // 500 <= 512
  float* csum = era + nf * 4;  // [nb,256]
  int* deg    = (int*)(csum + (size_t)nb * 256);
  int* rowptr = deg + n;
  int* cursor = rowptr + (n + 1);
  int* esrc   = cursor + n;
  int* bsum   = esrc + E;
  float* vv1  = (float*)(bsum + 256);  // [2][64]
  float* vv2  = vv1 + 128;             // [2][128]
  float* vvm  = vv2 + 256;             // [8][64]

  float* dsout = (float*)d_out;

  const int nwb  = (n + 3) / 4;
  const int eb   = (E + 255) / 256;
  const int nblk = (n + 255) / 256;

  // CSR of interacts graph by dst (shared by all three GAT layers)
  hipMemsetAsync(deg, 0, (size_t)n * sizeof(int), stream);
  k_hist<<<eb, 256, 0, stream>>>(dst0, deg, E);
  k_deg_bsum<<<nblk, 256, 0, stream>>>(deg, bsum, n);
  k_bsum_scan<<<1, 256, 0, stream>>>(bsum, nblk);
  k_rowptr<<<nblk, 256, 0, stream>>>(deg, bsum, rowptr, cursor, n, E);
  k_scatter<<<eb, 256, 0, stream>>>(src0, dst0, cursor, esrc, E);

  // attention logit vectors
  k_valvar_all<<<3, 128, 0, stream>>>(W1a, al1a, ar1a, W2a, al2a, ar2a, Wma, alma, arma,
                                      vv1, vv2, vvm);

  // layer 1: in=64 -> hid=128 (a+b fused)
  k_gemm2<64, 128, 1><<<(n + 63) / 64, 256, 0, stream>>>(x, W1a, W1b, vv1, A, B, ela, era, n);
  k_gat_h1<128><<<nwb, 256, 0, stream>>>(rowptr, esrc, A, ela, era, b1a, B, b1b, C, n);

  // layer 2: hid=128 -> out=64 (a+b fused)
  k_gemm2<128, 64, 1><<<(n + 31) / 32, 256, 0, stream>>>(C, W2a, W2b, vv2, A, B, ela, era, n);
  k_gat_h1<64><<<nwb, 256, 0, stream>>>(rowptr, esrc, A, ela, era, b2a, B, b2b, D2, n);

  // dh = chain_pass(h2)
  k_chainpass64<<<nwb, 256, 0, stream>>>(D2, E2, n);

  // MH layer: out=64 -> 4 heads x 64 (a+b fused)
  k_gemm2<64, 256, 4><<<(n + 63) / 64, 256, 0, stream>>>(E2, Wma, Wmb, vvm, A, B, ela, era, n);
  k_gat_mh<<<nwb, 256, 0, stream>>>(rowptr, esrc, A, ela, era, bma, B, bmb, C, n);

  // ds = chain_pass(hm) -> staged directly in d_out
  k_chainpass_mh<<<nwb, 256, 0, stream>>>(C, dsout, n);

  // res = cumsum(ds, axis=0), in-place in d_out
  k_chunk_sum<<<nb, 256, 0, stream>>>(dsout, csum, n, ch);
  k_scan_chunks_par<<<256, 512, 0, stream>>>(csum, nb);
  k_apply_scan<<<nb, 256, 0, stream>>>(dsout, csum, n, ch);
}

// Round 6
// 698.376 us; speedup vs baseline: 3.0183x; 1.0283x over previous
//
#include <hip/hip_runtime.h>
#include <math.h>

__device__ __forceinline__ float wred_sum(float v){
  #pragma unroll
  for (int o = 32; o > 0; o >>= 1) v += __shfl_xor(v, o);
  return v;
}
__device__ __forceinline__ float wred_max(float v){
  #pragma unroll
  for (int o = 32; o > 0; o >>= 1) v = fmaxf(v, __shfl_xor(v, o));
  return v;
}
__device__ __forceinline__ float lrelu(float v){ return v > 0.f ? v : 0.2f * v; }

// ---------------- CSR build (dst-sorted) ----------------
__global__ void k_hist(const int* __restrict__ dst, int* __restrict__ deg, int E){
  int t = blockIdx.x * blockDim.x + threadIdx.x;
  if (t < E) atomicAdd(&deg[dst[t]], 1);
}

__global__ void k_deg_bsum(const int* __restrict__ deg, int* __restrict__ bsum, int n){
  __shared__ int s[256];
  int b = blockIdx.x, t = threadIdx.x;
  int i = b * 256 + t;
  s[t] = (i < n) ? deg[i] : 0;
  __syncthreads();
  for (int o = 128; o > 0; o >>= 1){ if (t < o) s[t] += s[t + o]; __syncthreads(); }
  if (t == 0) bsum[b] = s[0];
}
__global__ void k_bsum_scan(int* __restrict__ bsum, int nblk){
  __shared__ int s[256];
  int t = threadIdx.x;
  s[t] = (t < nblk) ? bsum[t] : 0;
  __syncthreads();
  for (int o = 1; o < 256; o <<= 1){
    int add = (t >= o) ? s[t - o] : 0;
    __syncthreads();
    s[t] += add;
    __syncthreads();
  }
  if (t < nblk) bsum[t] = (t > 0) ? s[t - 1] : 0;
}
__global__ void k_rowptr(const int* __restrict__ deg, const int* __restrict__ bsum,
                         int* __restrict__ rowptr, int* __restrict__ cursor, int n, int E){
  __shared__ int s[256];
  int b = blockIdx.x, t = threadIdx.x;
  int i = b * 256 + t;
  int v = (i < n) ? deg[i] : 0;
  s[t] = v;
  __syncthreads();
  for (int o = 1; o < 256; o <<= 1){
    int add = (t >= o) ? s[t - o] : 0;
    __syncthreads();
    s[t] += add;
    __syncthreads();
  }
  if (i < n){
    int rp = bsum[b] + s[t] - v;
    rowptr[i] = rp;
    cursor[i] = rp;
    if (i == n - 1) rowptr[n] = E;
  }
}

__global__ void k_scatter(const int* __restrict__ src, const int* __restrict__ dst,
                          int* __restrict__ cursor, int* __restrict__ esrc, int E){
  int t = blockIdx.x * blockDim.x + threadIdx.x;
  if (t < E){
    int d = dst[t];
    int p = atomicAdd(&cursor[d], 1);
    esrc[p] = src[t];
  }
}

// ---------------- attention-logit weight precompute: vv = W^T {al, ar} ----------------
__global__ void k_valvar_all(const float* __restrict__ W1, const float* __restrict__ al1, const float* __restrict__ ar1,
                             const float* __restrict__ W2, const float* __restrict__ al2, const float* __restrict__ ar2,
                             const float* __restrict__ Wm, const float* __restrict__ alm, const float* __restrict__ arm,
                             float* __restrict__ vv1, float* __restrict__ vv2, float* __restrict__ vvm){
  int b = blockIdx.x, k = threadIdx.x;
  if (b == 0){
    if (k < 64){ // L1: K=64, C=128, H=1
      float v = 0.f, w = 0.f;
      for (int c = 0; c < 128; c++){ float ww = W1[c * 64 + k]; v += al1[c] * ww; w += ar1[c] * ww; }
      vv1[k] = v; vv1[64 + k] = w;
    }
  } else if (b == 1){ // L2: K=128, C=64, H=1
    float v = 0.f, w = 0.f;
    for (int c = 0; c < 64; c++){ float ww = W2[c * 128 + k]; v += al2[c] * ww; w += ar2[c] * ww; }
    vv2[k] = v; vv2[128 + k] = w;
  } else {
    if (k < 64){ // MH: K=64, C=256, H=4
      for (int h = 0; h < 4; h++){
        float v = 0.f, w = 0.f;
        for (int c = 0; c < 64; c++){
          float ww = Wm[(size_t)(h * 64 + c) * 64 + k];
          v += alm[h * 64 + c] * ww; w += arm[h * 64 + c] * ww;
        }
        vvm[(2 * h) * 64 + k] = v; vvm[(2 * h + 1) * 64 + k] = w;
      }
    }
  }
}

// ---------------- fused dual GEMM, 2 column-chunks per pass ----------------
// Chunk list = [a:cc0..ccN-1, b:cc0..ccN-1]; pair p = chunks (2p, 2p+1).
// Each XS broadcast read feeds 8 FMAs (2 cols x 4 k) -> VALU-bound, not LDS-bound.
// el/er computed as 2H extra columns from vv = W^T {al,ar}.
template<int K, int C, int H>
__global__ void k_gemm2(const float* __restrict__ x,
                        const float* __restrict__ Wa, const float* __restrict__ Wb,
                        const float* __restrict__ vv,
                        float* __restrict__ za, float* __restrict__ zb,
                        float* __restrict__ el, float* __restrict__ er, int n){
  constexpr int K4 = K / 4, NKC = K / 64, NCC = C / 64;
  constexpr int ROWS = 16384 / (K * 4);
  constexpr int RPW = ROWS / 4;
  constexpr int NP = NCC;           // (2*NCC chunks) / 2
  __shared__ float  XS[ROWS][K];
  __shared__ float4 WQ[2][16 * 65];

  int t = threadIdx.x, lane = t & 63, wv = t >> 6;
  int rowbase = blockIdx.x * ROWS;

  for (int idx = t; idx < ROWS * K4; idx += 256){
    int r = idx / K4, k4 = idx - r * K4;
    int row = rowbase + r;
    float4 v = make_float4(0.f, 0.f, 0.f, 0.f);
    if (row < n) v = *(const float4*)&x[(size_t)row * K + k4 * 4];
    *(float4*)&XS[r][k4 * 4] = v;
  }

  const int r0 = wv * RPW;
  float acc0[RPW], acc1[RPW];

  for (int p = 0; p < NP; p++){
    int q0 = 2 * p, q1 = q0 + 1;
    const float* Wp0 = (q0 < NCC) ? (Wa + (size_t)q0 * 64 * K) : (Wb + (size_t)(q0 - NCC) * 64 * K);
    const float* Wp1 = (q1 < NCC) ? (Wa + (size_t)q1 * 64 * K) : (Wb + (size_t)(q1 - NCC) * 64 * K);
    #pragma unroll
    for (int r = 0; r < RPW; r++){ acc0[r] = 0.f; acc1[r] = 0.f; }

    for (int kc = 0; kc < NKC; kc++){
      __syncthreads();
      const float4* A4 = (const float4*)Wp0;
      const float4* B4 = (const float4*)Wp1;
      for (int idx = t; idx < 1024; idx += 256){
        int c = idx >> 4, k4 = idx & 15;
        WQ[0][k4 * 65 + c] = A4[(size_t)c * K4 + kc * 16 + k4];
        WQ[1][k4 * 65 + c] = B4[(size_t)c * K4 + kc * 16 + k4];
      }
      __syncthreads();
      #pragma unroll 4
      for (int k4 = 0; k4 < 16; k4++){
        float4 w0 = WQ[0][k4 * 65 + lane];
        float4 w1 = WQ[1][k4 * 65 + lane];
        #pragma unroll
        for (int r = 0; r < RPW; r++){
          float4 xk = *(const float4*)&XS[r0 + r][kc * 64 + k4 * 4];
          acc0[r] += xk.x * w0.x + xk.y * w0.y + xk.z * w0.z + xk.w * w0.w;
          acc1[r] += xk.x * w1.x + xk.y * w1.y + xk.z * w1.z + xk.w * w1.w;
        }
      }
    }

    float* z0 = (q0 < NCC) ? za : zb;
    float* z1 = (q1 < NCC) ? za : zb;
    int c0 = ((q0 < NCC) ? q0 : q0 - NCC) * 64;
    int c1 = ((q1 < NCC) ? q1 : q1 - NCC) * 64;
    #pragma unroll
    for (int r = 0; r < RPW; r++){
      int row = rowbase + r0 + r;
      if (row < n){
        z0[(size_t)row * C + c0 + lane] = acc0[r];
        z1[(size_t)row * C + c1 + lane] = acc1[r];
      }
    }
  }

  // ext chunk: cols 0..2H-1 of vv -> el/er (lanes >= 2H compute garbage, unwritten)
  {
    #pragma unroll
    for (int r = 0; r < RPW; r++) acc0[r] = 0.f;
    for (int kc = 0; kc < NKC; kc++){
      __syncthreads();
      const float4* V4 = (const float4*)vv;
      for (int idx = t; idx < 2 * H * 16; idx += 256){
        int c = idx >> 4, k4 = idx & 15;
        WQ[0][k4 * 65 + c] = V4[(size_t)c * K4 + kc * 16 + k4];
      }
      __syncthreads();
      #pragma unroll 4
      for (int k4 = 0; k4 < 16; k4++){
        float4 w0 = WQ[0][k4 * 65 + lane];
        #pragma unroll
        for (int r = 0; r < RPW; r++){
          float4 xk = *(const float4*)&XS[r0 + r][kc * 64 + k4 * 4];
          acc0[r] += xk.x * w0.x + xk.y * w0.y + xk.z * w0.z + xk.w * w0.w;
        }
      }
    }
    if (lane < 2 * H){
      int h = lane >> 1;
      float* dst = (lane & 1) ? er : el;
      #pragma unroll
      for (int r = 0; r < RPW; r++){
        int row = rowbase + r0 + r;
        if (row < n) dst[(size_t)row * H + h] = acc0[r];
      }
    }
  }
}

// ---------------- GAT aggregation, 1 head, fused with chain-shift + mean ----------------
template<int D>
__global__ void k_gat_h1(const int* __restrict__ rowptr, const int* __restrict__ esrc,
                         const float* __restrict__ z, const float* __restrict__ el,
                         const float* __restrict__ er, const float* __restrict__ b,
                         const float* __restrict__ zb, const float* __restrict__ bb,
                         float* __restrict__ out, int n){
  constexpr int DR = D / 64;
  int lane = threadIdx.x & 63;
  int i = blockIdx.x * (blockDim.x >> 6) + (threadIdx.x >> 6);
  if (i >= n) return;
  int s0 = rowptr[i], s1 = rowptr[i + 1];
  float eri = er[i];
  float m = -INFINITY;
  for (int e = s0 + lane; e < s1; e += 64)
    m = fmaxf(m, lrelu(el[esrc[e]] + eri));
  m = wred_max(m);
  float den = 0.f, den2 = 0.f;
  float acc[DR], acc2[DR];
  #pragma unroll
  for (int j = 0; j < DR; j++){ acc[j] = 0.f; acc2[j] = 0.f; }
  int e = s0;
  for (; e + 1 < s1; e += 2){
    int sA = esrc[e], sB = esrc[e + 1];
    float wA = __expf(lrelu(el[sA] + eri) - m);
    float wB = __expf(lrelu(el[sB] + eri) - m);
    den += wA; den2 += wB;
    const float* zA = z + (size_t)sA * D;
    const float* zB = z + (size_t)sB * D;
    #pragma unroll
    for (int j = 0; j < DR; j++){
      acc[j]  += wA * zA[j * 64 + lane];
      acc2[j] += wB * zB[j * 64 + lane];
    }
  }
  if (e < s1){
    int sA = esrc[e];
    float wA = __expf(lrelu(el[sA] + eri) - m);
    den += wA;
    const float* zA = z + (size_t)sA * D;
    #pragma unroll
    for (int j = 0; j < DR; j++) acc[j] += wA * zA[j * 64 + lane];
  }
  den += den2;
  float inv = (s1 > s0) ? 1.f / den : 0.f;
  float* op = out + (size_t)i * D;
  #pragma unroll
  for (int j = 0; j < DR; j++){
    int c = j * 64 + lane;
    float chain = bb[c];
    if (i > 0) chain += zb[(size_t)(i - 1) * D + c];
    op[c] = 0.5f * (((acc[j] + acc2[j]) * inv + b[c]) + chain);
  }
}

// ---------------- GAT aggregation, 4 heads x 64 dims ----------------
__global__ void k_gat_mh(const int* __restrict__ rowptr, const int* __restrict__ esrc,
                         const float* __restrict__ z, const float* __restrict__ el,
                         const float* __restrict__ er, const float* __restrict__ b,
                         const float* __restrict__ zb, const float* __restrict__ bb,
                         float* __restrict__ out, int n){
  int lane = threadIdx.x & 63;
  int i = blockIdx.x * (blockDim.x >> 6) + (threadIdx.x >> 6);
  if (i >= n) return;
  int s0 = rowptr[i], s1 = rowptr[i + 1];
  const float4 eri = *(const float4*)(er + (size_t)i * 4);
  float m0 = -INFINITY, m1 = -INFINITY, m2 = -INFINITY, m3 = -INFINITY;
  for (int e = s0 + lane; e < s1; e += 64){
    float4 e4 = *(const float4*)(el + (size_t)esrc[e] * 4);
    m0 = fmaxf(m0, lrelu(e4.x + eri.x));
    m1 = fmaxf(m1, lrelu(e4.y + eri.y));
    m2 = fmaxf(m2, lrelu(e4.z + eri.z));
    m3 = fmaxf(m3, lrelu(e4.w + eri.w));
  }
  m0 = wred_max(m0); m1 = wred_max(m1); m2 = wred_max(m2); m3 = wred_max(m3);
  float d0 = 0.f, d1 = 0.f, d2 = 0.f, d3 = 0.f;
  float a0 = 0.f, a1 = 0.f, a2 = 0.f, a3 = 0.f;
  float d0B = 0.f, d1B = 0.f, d2B = 0.f, d3B = 0.f;
  float a0B = 0.f, a1B = 0.f, a2B = 0.f, a3B = 0.f;
  int e = s0;
  for (; e + 1 < s1; e += 2){
    int sA = esrc[e], sB = esrc[e + 1];
    float4 eA = *(const float4*)(el + (size_t)sA * 4);
    float4 eB = *(const float4*)(el + (size_t)sB * 4);
    const float* zA = z + (size_t)sA * 256;
    const float* zB = z + (size_t)sB * 256;
    float w0 = __expf(lrelu(eA.x + eri.x) - m0);
    float w1 = __expf(lrelu(eA.y + eri.y) - m1);
    float w2 = __expf(lrelu(eA.z + eri.z) - m2);
    float w3 = __expf(lrelu(eA.w + eri.w) - m3);
    float v0 = __expf(lrelu(eB.x + eri.x) - m0);
    float v1 = __expf(lrelu(eB.y + eri.y) - m1);
    float v2 = __expf(lrelu(eB.z + eri.z) - m2);
    float v3 = __expf(lrelu(eB.w + eri.w) - m3);
    d0 += w0; d1 += w1; d2 += w2; d3 += w3;
    d0B += v0; d1B += v1; d2B += v2; d3B += v3;
    a0 += w0 * zA[lane];        a0B += v0 * zB[lane];
    a1 += w1 * zA[64 + lane];   a1B += v1 * zB[64 + lane];
    a2 += w2 * zA[128 + lane];  a2B += v2 * zB[128 + lane];
    a3 += w3 * zA[192 + lane];  a3B += v3 * zB[192 + lane];
  }
  if (e < s1){
    int sA = esrc[e];
    float4 eA = *(const float4*)(el + (size_t)sA * 4);
    const float* zA = z + (size_t)sA * 256;
    float w0 = __expf(lrelu(eA.x + eri.x) - m0);
    float w1 = __expf(lrelu(eA.y + eri.y) - m1);
    float w2 = __expf(lrelu(eA.z + eri.z) - m2);
    float w3 = __expf(lrelu(eA.w + eri.w) - m3);
    d0 += w0; d1 += w1; d2 += w2; d3 += w3;
    a0 += w0 * zA[lane];
    a1 += w1 * zA[64 + lane];
    a2 += w2 * zA[128 + lane];
    a3 += w3 * zA[192 + lane];
  }
  d0 += d0B; d1 += d1B; d2 += d2B; d3 += d3B;
  a0 += a0B; a1 += a1B; a2 += a2B; a3 += a3B;
  float has = (s1 > s0) ? 1.f : 0.f;
  a0 = (has != 0.f) ? a0 / d0 : 0.f;
  a1 = (has != 0.f) ? a1 / d1 : 0.f;
  a2 = (has != 0.f) ? a2 / d2 : 0.f;
  a3 = (has != 0.f) ? a3 / d3 : 0.f;
  float* op = out + (size_t)i * 256;
  float av[4] = {a0, a1, a2, a3};
  #pragma unroll
  for (int h = 0; h < 4; h++){
    int c = h * 64 + lane;
    float chain = bb[c];
    if (i > 0) chain += zb[(size_t)(i - 1) * 256 + c];
    op[c] = 0.5f * ((av[h] + b[c]) + chain);
  }
}

// ---------------- chain_pass ----------------
__global__ void k_chainpass64(const float* __restrict__ h, float* __restrict__ dh, int n){
  int lane = threadIdx.x & 63;
  int i = blockIdx.x * (blockDim.x >> 6) + (threadIdx.x >> 6);
  if (i >= n) return;
  float d = 0.f;
  if (i > 0) d = h[(size_t)(i - 1) * 64 + lane] - h[(size_t)i * 64 + lane];
  float ss = wred_sum(d * d);
  dh[(size_t)i * 64 + lane] = d / (sqrtf(ss) + 1e-7f);
}

__global__ void k_chainpass_mh(const float* __restrict__ hm, float* __restrict__ ds, int n){
  int lane = threadIdx.x & 63;
  int i = blockIdx.x * (blockDim.x >> 6) + (threadIdx.x >> 6);
  if (i >= n) return;
  const float* cur = hm + (size_t)i * 256;
  const float* prv = hm + (size_t)(i - 1) * 256;
  #pragma unroll
  for (int h = 0; h < 4; h++){
    int c = h * 64 + lane;
    float d = (i > 0) ? (prv[c] - cur[c]) : 0.f;
    float ss = wred_sum(d * d);
    ds[(size_t)i * 256 + c] = d / (sqrtf(ss) + 1e-7f);
  }
}

// ---------------- column-wise prefix sum over nodes (256 cols) ----------------
__global__ void k_chunk_sum(const float* __restrict__ ds, float* __restrict__ csum, int n, int ch){
  int b = blockIdx.x, t = threadIdx.x;
  int r0 = b * ch, r1 = r0 + ch; if (r1 > n) r1 = n;
  float s = 0.f;
  for (int r = r0; r < r1; r++) s += ds[(size_t)r * 256 + t];
  csum[(size_t)b * 256 + t] = s;
}
__global__ void k_scan_chunks_par(float* __restrict__ csum, int nb){
  __shared__ float s[512];
  int col = blockIdx.x;
  int t = threadIdx.x;
  s[t] = (t < nb) ? csum[(size_t)t * 256 + col] : 0.f;
  __syncthreads();
  #pragma unroll
  for (int o = 1; o < 512; o <<= 1){
    float add = (t >= o) ? s[t - o] : 0.f;
    __syncthreads();
    s[t] += add;
    __syncthreads();
  }
  if (t < nb) csum[(size_t)t * 256 + col] = (t > 0) ? s[t - 1] : 0.f;
}
__global__ void k_apply_scan(float* __restrict__ ds, const float* __restrict__ csum, int n, int ch){
  int b = blockIdx.x, t = threadIdx.x;
  int r0 = b * ch, r1 = r0 + ch; if (r1 > n) r1 = n;
  float run = csum[(size_t)b * 256 + t];
  for (int r = r0; r < r1; r++){
    run += ds[(size_t)r * 256 + t];
    ds[(size_t)r * 256 + t] = run;
  }
}

extern "C" void kernel_launch(void* const* d_in, const int* in_sizes, int n_in,
                              void* d_out, int out_size, void* d_ws, size_t ws_size,
                              hipStream_t stream){
  const float* x    = (const float*)d_in[0];
  const int*   src0 = (const int*)d_in[1];
  const int*   dst0 = (const int*)d_in[2];
  const float* W1a  = (const float*)d_in[5];
  const float* al1a = (const float*)d_in[6];
  const float* ar1a = (const float*)d_in[7];
  const float* b1a  = (const float*)d_in[8];
  const float* W1b  = (const float*)d_in[9];
  const float* b1b  = (const float*)d_in[12];
  const float* W2a  = (const float*)d_in[13];
  const float* al2a = (const float*)d_in[14];
  const float* ar2a = (const float*)d_in[15];
  const float* b2a  = (const float*)d_in[16];
  const float* W2b  = (const float*)d_in[17];
  const float* b2b  = (const float*)d_in[20];
  const float* Wma  = (const float*)d_in[21];
  const float* alma = (const float*)d_in[22];
  const float* arma = (const float*)d_in[23];
  const float* bma  = (const float*)d_in[24];
  const float* Wmb  = (const float*)d_in[25];
  const float* bmb  = (const float*)d_in[28];

  const int n = in_sizes[0] / 64;
  const int E = in_sizes[1];
  const size_t nf = (size_t)n;

  float* ws  = (float*)d_ws;
  float* A   = ws;
  float* B   = A + nf * 256;
  float* C   = B + nf * 256;
  float* D2  = C + nf * 256;   // h2 [n,64]
  float* E2  = D2 + nf * 64;   // dh [n,64]
  float* ela = E2 + nf * 64;   // [n,4]
  float* era = ela + nf * 4;
  const int ch = 100;
  const int nb = (n + ch - 1) / ch;      // 500 <= 512
  float* csum = era + nf * 4;  // [nb,256]
  int* deg    = (int*)(csum + (size_t)nb * 256);
  int* rowptr = deg + n;
  int* cursor = rowptr + (n + 1);
  int* esrc   = cursor + n;
  int* bsum   = esrc + E;
  float* vv1  = (float*)(bsum + 256);  // [2][64]
  float* vv2  = vv1 + 128;             // [2][128]
  float* vvm  = vv2 + 256;             // [8][64]

  float* dsout = (float*)d_out;

  const int nwb  = (n + 3) / 4;
  const int eb   = (E + 255) / 256;
  const int nblk = (n + 255) / 256;

  // CSR of interacts graph by dst (shared by all three GAT layers)
  hipMemsetAsync(deg, 0, (size_t)n * sizeof(int), stream);
  k_hist<<<eb, 256, 0, stream>>>(dst0, deg, E);
  k_deg_bsum<<<nblk, 256, 0, stream>>>(deg, bsum, n);
  k_bsum_scan<<<1, 256, 0, stream>>>(bsum, nblk);
  k_rowptr<<<nblk, 256, 0, stream>>>(deg, bsum, rowptr, cursor, n, E);
  k_scatter<<<eb, 256, 0, stream>>>(src0, dst0, cursor, esrc, E);

  // attention logit vectors
  k_valvar_all<<<3, 128, 0, stream>>>(W1a, al1a, ar1a, W2a, al2a, ar2a, Wma, alma, arma,
                                      vv1, vv2, vvm);

  // layer 1: in=64 -> hid=128 (a+b fused)
  k_gemm2<64, 128, 1><<<(n + 63) / 64, 256, 0, stream>>>(x, W1a, W1b, vv1, A, B, ela, era, n);
  k_gat_h1<128><<<nwb, 256, 0, stream>>>(rowptr, esrc, A, ela, era, b1a, B, b1b, C, n);

  // layer 2: hid=128 -> out=64 (a+b fused)
  k_gemm2<128, 64, 1><<<(n + 31) / 32, 256, 0, stream>>>(C, W2a, W2b, vv2, A, B, ela, era, n);
  k_gat_h1<64><<<nwb, 256, 0, stream>>>(rowptr, esrc, A, ela, era, b2a, B, b2b, D2, n);

  // dh = chain_pass(h2)
  k_chainpass64<<<nwb, 256, 0, stream>>>(D2, E2, n);

  // MH layer: out=64 -> 4 heads x 64 (a+b fused)
  k_gemm2<64, 256, 4><<<(n + 63) / 64, 256, 0, stream>>>(E2, Wma, Wmb, vvm, A, B, ela, era, n);
  k_gat_mh<<<nwb, 256, 0, stream>>>(rowptr, esrc, A, ela, era, bma, B, bmb, C, n);

  // ds = chain_pass(hm) -> staged directly in d_out
  k_chainpass_mh<<<nwb, 256, 0, stream>>>(C, dsout, n);

  // res = cumsum(ds, axis=0), in-place in d_out
  k_chunk_sum<<<nb, 256, 0, stream>>>(dsout, csum, n, ch);
  k_scan_chunks_par<<<256, 512, 0, stream>>>(csum, nb);
  k_apply_scan<<<nb, 256, 0, stream>>>(dsout, csum, n, ch);
}